// Round 3
// baseline (358.195 us; speedup 1.0000x reference)
//
#include <hip/hip_runtime.h>
#include <hip/hip_bf16.h>

#define Bn 16
#define Cn 512
#define Nn 4096

typedef unsigned short u16;
typedef __bf16 bf16x8 __attribute__((ext_vector_type(8)));
typedef float f32x4 __attribute__((ext_vector_type(4)));
typedef unsigned short u16x8 __attribute__((ext_vector_type(8)));

__device__ __forceinline__ u16 f2bf(float f) {
    __hip_bfloat16 h = __float2bfloat16(f);
    return *reinterpret_cast<u16*>(&h);
}

// async global->LDS, 16B per lane; LDS dest is wave-uniform base + lane*16
__device__ __forceinline__ void glds16(const u16* g, u16* l) {
    __builtin_amdgcn_global_load_lds(
        (const __attribute__((address_space(1))) void*)g,
        (__attribute__((address_space(3))) void*)l, 16, 0, 0);
}

// ---------------------------------------------------------------------------
// K1: x (B,C,N) fp32 -> x_t (B,N,C) bf16, plus per-(b,c) partial sums over the
// 64-wide n-tile. 128c x 64n tile: 256B segments on both read and write sides.
// ---------------------------------------------------------------------------
__global__ __launch_bounds__(256) void k_transpose(
    const float* __restrict__ x, u16* __restrict__ xt, float* __restrict__ sxp)
{
    __shared__ float tile[128 * 65];
    const int b = blockIdx.z, c0 = blockIdx.y * 128, n0 = blockIdx.x * 64;
    const int t = threadIdx.x;
    const float* xb = x + ((size_t)(b * Cn + c0)) * Nn + n0;

    float part[8];
#pragma unroll
    for (int r = 0; r < 8; ++r) {
        int cl = (t >> 4) + r * 16;
        int nl = (t & 15) * 4;
        float4 v = *(const float4*)(xb + (size_t)cl * Nn + nl);
        float* tp = &tile[cl * 65 + nl];
        tp[0] = v.x; tp[1] = v.y; tp[2] = v.z; tp[3] = v.w;
        part[r] = (v.x + v.y) + (v.z + v.w);
    }
#pragma unroll
    for (int m = 1; m < 16; m <<= 1) {
#pragma unroll
        for (int r = 0; r < 8; ++r) part[r] += __shfl_xor(part[r], m);
    }
    if ((t & 15) == 0) {
#pragma unroll
        for (int r = 0; r < 8; ++r) {
            int cl = (t >> 4) + r * 16;
            sxp[(size_t)(b * Cn + c0 + cl) * 64 + blockIdx.x] = part[r];
        }
    }
    __syncthreads();
    u16* xtb = xt + ((size_t)(b * Nn + n0)) * Cn + c0;
#pragma unroll
    for (int r = 0; r < 4; ++r) {
        int nl = (t >> 4) + r * 16;
        int c8 = (t & 15) * 8;
        u16x8 hv;
#pragma unroll
        for (int i = 0; i < 8; ++i) hv[i] = f2bf(tile[(c8 + i) * 65 + nl]);
        *(u16x8*)(xtb + (size_t)nl * Cn + c8) = hv;
    }
}

// K1b: reduce 64 n-tile partials -> Sx[b*C+c]
__global__ __launch_bounds__(256) void k_sxred(
    const float* __restrict__ sxp, float* __restrict__ sx)
{
    int i = blockIdx.x * 256 + threadIdx.x;  // 0..8191
    const float4* p = (const float4*)(sxp + (size_t)i * 64);
    float s = 0.f;
#pragma unroll
    for (int j = 0; j < 16; ++j) {
        float4 v = p[j];
        s += (v.x + v.y) + (v.z + v.w);
    }
    sx[i] = s;
}

// K2: qy[b,o] = wq@y + bq ; sk[b,o] = wk@Sx + N*bk. One wave per output.
__global__ __launch_bounds__(256) void k_qk(
    const float* __restrict__ wq, const float* __restrict__ bq,
    const float* __restrict__ wk, const float* __restrict__ bk,
    const float* __restrict__ y, const float* __restrict__ sx,
    float* __restrict__ qy, float* __restrict__ sk)
{
    const int w = threadIdx.x >> 6, lane = threadIdx.x & 63;
    const int o = blockIdx.x * 4 + w;
    const int b = blockIdx.y;
    const int mode = blockIdx.z;
    const float* W = mode ? wk : wq;
    const float* vec = mode ? (sx + b * Cn) : (y + b * Cn);
    float sum = 0.f;
#pragma unroll
    for (int i = 0; i < 8; ++i) {
        int k2 = lane + i * 64;
        sum += W[(size_t)o * Cn + k2] * vec[k2];
    }
#pragma unroll
    for (int m = 1; m < 64; m <<= 1) sum += __shfl_xor(sum, m);
    if (lane == 0) {
        if (mode) sk[b * Cn + o] = sum + 4096.0f * bk[o];
        else      qy[b * Cn + o] = sum + bq[o];
    }
}

// K2b: wv_t[e,d] = bf16(wv[d,e]) via 64x64 LDS tile (coalesced both sides)
__global__ __launch_bounds__(256) void k_wvt(
    const float* __restrict__ wv, u16* __restrict__ wvt)
{
    __shared__ float tl[64 * 65];
    const int d0 = blockIdx.x * 64, e0 = blockIdx.y * 64;
    const int t = threadIdx.x;
#pragma unroll
    for (int r = 0; r < 4; ++r) {
        int d = (t >> 4) + r * 16, e4 = (t & 15) * 4;
        float4 v = *(const float4*)(wv + (size_t)(d0 + d) * Cn + e0 + e4);
        float* p = &tl[d * 65 + e4];
        p[0] = v.x; p[1] = v.y; p[2] = v.z; p[3] = v.w;
    }
    __syncthreads();
#pragma unroll
    for (int r = 0; r < 4; ++r) {
        int e = (t >> 4) + r * 16, d4 = (t & 15) * 4;
        ushort4 h;
        h.x = f2bf(tl[(d4 + 0) * 65 + e]);
        h.y = f2bf(tl[(d4 + 1) * 65 + e]);
        h.z = f2bf(tl[(d4 + 2) * 65 + e]);
        h.w = f2bf(tl[(d4 + 3) * 65 + e]);
        *(ushort4*)(wvt + (size_t)(e0 + e) * Cn + d0 + d4) = h;
    }
}

// K3: per (b,c) row: softmax_d(qy*sk) -> attn (bf16), beff = attn . bv (fp32)
__global__ __launch_bounds__(256) void k_softmax(
    const float* __restrict__ qy, const float* __restrict__ sk,
    const float* __restrict__ bv, u16* __restrict__ attn,
    float* __restrict__ beff)
{
    __shared__ float red[4], red2[4], red3[4];
    const int b = blockIdx.x >> 9, c = blockIdx.x & 511;
    const int t = threadIdx.x;
    const float q = qy[b * Cn + c];
    const float l0 = q * sk[b * Cn + t];
    const float l1 = q * sk[b * Cn + t + 256];
    float mx = fmaxf(l0, l1);
#pragma unroll
    for (int m = 1; m < 64; m <<= 1) mx = fmaxf(mx, __shfl_xor(mx, m));
    if ((t & 63) == 0) red[t >> 6] = mx;
    __syncthreads();
    mx = fmaxf(fmaxf(red[0], red[1]), fmaxf(red[2], red[3]));
    const float e0 = __expf(l0 - mx), e1 = __expf(l1 - mx);
    float s = e0 + e1;
#pragma unroll
    for (int m = 1; m < 64; m <<= 1) s += __shfl_xor(s, m);
    if ((t & 63) == 0) red2[t >> 6] = s;
    __syncthreads();
    s = red2[0] + red2[1] + red2[2] + red2[3];
    const float inv = 1.0f / s;
    const float a0 = e0 * inv, a1 = e1 * inv;
    u16* arow = attn + ((size_t)(b * Cn + c)) * Cn;
    arow[t] = f2bf(a0);
    arow[t + 256] = f2bf(a1);
    float pb = a0 * bv[t] + a1 * bv[t + 256];
#pragma unroll
    for (int m = 1; m < 64; m <<= 1) pb += __shfl_xor(pb, m);
    if ((t & 63) == 0) red3[t >> 6] = pb;
    __syncthreads();
    if (t == 0) beff[b * Cn + c] = red3[0] + red3[1] + red3[2] + red3[3];
}

// ---------------------------------------------------------------------------
// Shared MFMA GEMM (old 128x128 structure) — still used for Weff = attn @ wv,
// and as a fallback for the final GEMM if dynamic-LDS setup fails.
// ---------------------------------------------------------------------------
template <int FINAL>
__global__ __launch_bounds__(256) void k_gemm(
    const u16* __restrict__ A, size_t strideA,
    const u16* __restrict__ Bt, size_t strideB,
    int N,
    u16* __restrict__ outBf, size_t strideOb,
    float* __restrict__ outF,
    const float* __restrict__ xres,
    const float* __restrict__ beff,
    const float* __restrict__ gamma)
{
    constexpr int K = 512;
    __shared__ float smem_f[8448];          // 33,792 B: K-loop 32KB / epi 33KB
    u16* la = (u16*)smem_f;                 // [128*64] bf16
    u16* lb = la + 128 * 64;
    const int b = blockIdx.z;
    const int m0 = blockIdx.y * 128;
    const int n0 = blockIdx.x * 128;
    A  += (size_t)b * strideA;
    Bt += (size_t)b * strideB;
    const int t = threadIdx.x;
    const int lane = t & 63;
    const int w = t >> 6;
    const int wm = (w >> 1) * 64, wn = (w & 1) * 64;
    const int l15 = lane & 15, quad = lane >> 4;

    f32x4 acc[4][4];
#pragma unroll
    for (int i = 0; i < 4; ++i)
#pragma unroll
        for (int j = 0; j < 4; ++j)
            acc[i][j] = (f32x4){0.f, 0.f, 0.f, 0.f};

    const int srow8 = lane >> 3;                 // 0..7
    const int lgcol = ((lane & 7) ^ srow8) * 8;  // logical k-col (swizzled)

    for (int k0 = 0; k0 < K; k0 += 64) {
        __syncthreads();
#pragma unroll
        for (int j = 0; j < 4; ++j) {
            const int row = w * 32 + j * 8 + srow8;
            const int sb = (w * 256 + j * 64) * 8;   // u16 offset of slot base
            glds16(A  + (size_t)(m0 + row) * K + k0 + lgcol, la + sb);
            glds16(Bt + (size_t)(n0 + row) * K + k0 + lgcol, lb + sb);
        }
        __syncthreads();

#pragma unroll
        for (int kk2 = 0; kk2 < 2; ++kk2) {
            bf16x8 af[4], bfr[4];
#pragma unroll
            for (int mi = 0; mi < 4; ++mi) {
                const int r = wm + mi * 16 + l15;
                const int pg = ((kk2 << 2) + quad) ^ (l15 & 7);
                af[mi] = *(const bf16x8*)&la[r * 64 + pg * 8];
            }
#pragma unroll
            for (int ni = 0; ni < 4; ++ni) {
                const int r = wn + ni * 16 + l15;
                const int pg = ((kk2 << 2) + quad) ^ (l15 & 7);
                bfr[ni] = *(const bf16x8*)&lb[r * 64 + pg * 8];
            }
#pragma unroll
            for (int mi = 0; mi < 4; ++mi)
#pragma unroll
                for (int ni = 0; ni < 4; ++ni)
                    acc[mi][ni] = __builtin_amdgcn_mfma_f32_16x16x32_bf16(
                        af[mi], bfr[ni], acc[mi][ni], 0, 0, 0);
        }
    }

    if (FINAL) {
        const float g = gamma[0];
        float* lc = smem_f;                  // 64 rows x stride 132 fp32
#pragma unroll
        for (int h = 0; h < 2; ++h) {
            __syncthreads();
            if ((w >> 1) == h) {
#pragma unroll
                for (int mi = 0; mi < 4; ++mi)
#pragma unroll
                    for (int reg = 0; reg < 4; ++reg) {
                        const int rl = mi * 16 + quad * 4 + reg;
#pragma unroll
                        for (int ni = 0; ni < 4; ++ni)
                            lc[rl * 132 + wn + ni * 16 + l15] = acc[mi][ni][reg];
                    }
            }
            __syncthreads();
            const int rb = h * 64;
#pragma unroll
            for (int rr = 0; rr < 8; ++rr) {
                const int rl = rr * 8 + (t >> 5);
                const int c4 = (t & 31) * 4;
                float4 v = *(float4*)&lc[rl * 132 + c4];
                const int r = m0 + rb + rl;
                const float be = beff[b * Cn + r];
                const size_t base = ((size_t)(b * Cn + r)) * N + n0 + c4;
                float4 xr = *(const float4*)(xres + base);
                float4 o;
                o.x = g * (v.x + be) + xr.x;
                o.y = g * (v.y + be) + xr.y;
                o.z = g * (v.z + be) + xr.z;
                o.w = g * (v.w + be) + xr.w;
                *(float4*)(outF + base) = o;
            }
        }
    } else {
#pragma unroll
        for (int mi = 0; mi < 4; ++mi) {
#pragma unroll
            for (int reg = 0; reg < 4; ++reg) {
                const int r = m0 + wm + mi * 16 + quad * 4 + reg;
                const size_t base = (size_t)b * strideOb + (size_t)r * N;
#pragma unroll
                for (int ni = 0; ni < 4; ++ni) {
                    const int cidx = n0 + wn + ni * 16 + l15;
                    outBf[base + cidx] = f2bf(acc[mi][ni][reg]);
                }
            }
        }
    }
}

// ---------------------------------------------------------------------------
// k_gemm2 (round 3): final GEMM out = gamma*(Weff@x + beff) + x.
// 256x128 tile, BK=32, 8 waves (4Mx2N), wave-tile 64x64, acc=64 AGPR,
// launch_bounds(512,4) -> 4 waves/SIMD; LDS 72KiB -> 2 blocks/CU (same
// footprint as round 2, which showed 2-block residency).
// Asymmetric rings matched to operand latency:
//   A (weff, L2-hot 0.5MB/batch): ring-2 x 16KB, prefetch depth 1.
//   B (xt, LLC/HBM stream):       ring-5 x 8KB,  prefetch depth 4 (~1200cy).
// Per tile j: wait vmcnt(1) (forces A(j),B(j); leaves B(j+3) in flight),
// one raw s_barrier, issue A(j+1) then B(j+4), 8 ds_read_b128, 16 MFMA.
// Slot-disjointness: A writes (j+1)&1 vs reads j&1; B writes (j+4)%5 vs
// reads j%5 (5 consecutive residues distinct). XOR k-group swizzle as before
// (conflict-free verified). XCD swizzle: pair the two m-panels of each
// n-panel (and 4 adjacent n-panels) on one XCD for L2 reuse of xt.
// ---------------------------------------------------------------------------
__global__ __launch_bounds__(512, 4) void k_gemm2(
    const u16* __restrict__ A,    // weff (B,512,512) bf16
    const u16* __restrict__ Bt,   // xt   (B,4096,512) bf16
    float* __restrict__ outF,
    const float* __restrict__ xres,
    const float* __restrict__ beff,
    const float* __restrict__ gamma)
{
    extern __shared__ u16 sm[];   // 73728 B = A ring-2 x 16KB + B ring-5 x 8KB
    const int b = blockIdx.z;
    // XCD-pair swizzle: f in [0,64): xcd=f&7, s=f>>3.
    // n_panel = xcd*4 + (s>>1) in [0,32), m_panel = s&1. Bijective; dispatch
    // index ~ f + 64*z so xcd assignment is consistent per batch.
    const int f = blockIdx.x + (blockIdx.y << 5);
    const int xcd = f & 7, sl = f >> 3;
    const int m0 = (sl & 1) << 8;                  // 256-row panel
    const int n0 = ((xcd << 2) + (sl >> 1)) << 7;  // 128-col panel
    const int t = threadIdx.x;
    const int lane = t & 63, w = t >> 6;
    const int wm = (w >> 1) << 6, wn = (w & 1) << 6;
    const int l15 = lane & 15, quad = lane >> 4;

    const u16* Ag = A + (size_t)b * Cn * Cn;
    const u16* Bg = Bt + (size_t)b * ((size_t)Nn * Cn);
    // staging: thread t covers LDS u16 [t*8 .. t*8+8) of its chunk;
    // row = t>>2 (within 128-row chunk), phys group t&3 holds logical group
    // (t&3)^((row>>1)&3) -> pre-swizzled global column.
    const int srow = t >> 2;
    const int scol = (((t & 3) ^ ((srow >> 1) & 3))) << 3;
    const u16* pa = Ag + (size_t)(m0 + srow) * Cn + scol;
    const u16* pb = Bg + (size_t)(n0 + srow) * Cn + scol;
    const int dwo = w * 512;      // wave-uniform dest offset within a chunk

    // A slot s(0..1): u16 off s*8192, chunk c adds c*4096 (rows 128c..).
    // B slot s(0..4): u16 off 16384 + s*4096.
#define STGA(s, c, k0) \
    glds16(pa + (size_t)(c) * (128 * Cn) + (k0), \
           sm + (s) * 8192 + (c) * 4096 + dwo)
#define STGB(s, k0) glds16(pb + (k0), sm + 16384 + (s) * 4096 + dwo)
#define FRGA(s, row, qd) \
    (*(const bf16x8*)&sm[(s) * 8192 + (row) * 32 + \
                         (((qd) ^ (((row) >> 1) & 3)) << 3)])
#define FRGB(s, row, qd) \
    (*(const bf16x8*)&sm[16384 + (s) * 4096 + (row) * 32 + \
                         (((qd) ^ (((row) >> 1) & 3)) << 3)])

    f32x4 acc[4][4];
#pragma unroll
    for (int i = 0; i < 4; ++i)
#pragma unroll
        for (int j = 0; j < 4; ++j) acc[i][j] = (f32x4){0.f, 0.f, 0.f, 0.f};

    // prologue: A(0) (2 loads), B(0..3) (4 loads); issue order fixes ledger
    STGA(0, 0, 0); STGA(0, 1, 0);
    STGB(0, 0); STGB(1, 32); STGB(2, 64); STGB(3, 96);

#pragma unroll
    for (int tI = 0; tI < 16; ++tI) {
        // ledger (steady j in [1,12]): outstanding oldest->newest =
        // B(j),B(j+1),B(j+2),A(j)x2,B(j+3) -> need through A(j) => vmcnt(1).
        // j==0: A0x2,B0..B3 -> need A0,B0 => vmcnt(3). j>=13: A(j) newest => 0.
        if (tI == 0)       { asm volatile("s_waitcnt vmcnt(3)" ::: "memory"); }
        else if (tI <= 12) { asm volatile("s_waitcnt vmcnt(1)" ::: "memory"); }
        else               { asm volatile("s_waitcnt vmcnt(0)" ::: "memory"); }
        __builtin_amdgcn_s_barrier();   // tile tI visible; all waves done
                                        // reading the slots being overwritten
        if (tI + 1 <= 15) {             // A depth-1: stage A(tI+1), slot (tI+1)&1
            STGA((tI + 1) & 1, 0, (tI + 1) << 5);
            STGA((tI + 1) & 1, 1, (tI + 1) << 5);
        }
        if (tI + 4 <= 15) {             // B depth-4: stage B(tI+4), slot (tI+4)%5
            STGB((tI + 4) % 5, (tI + 4) << 5);
        }
        const int sa = tI & 1, sb5 = tI % 5;
        bf16x8 af[4], bf[4];
#pragma unroll
        for (int mi = 0; mi < 4; ++mi)
            af[mi] = FRGA(sa, wm + mi * 16 + l15, quad);
#pragma unroll
        for (int ni = 0; ni < 4; ++ni)
            bf[ni] = FRGB(sb5, wn + ni * 16 + l15, quad);
        __builtin_amdgcn_s_setprio(1);
#pragma unroll
        for (int mi = 0; mi < 4; ++mi)
#pragma unroll
            for (int ni = 0; ni < 4; ++ni)
                acc[mi][ni] = __builtin_amdgcn_mfma_f32_16x16x32_bf16(
                    af[mi], bf[ni], acc[mi][ni], 0, 0, 0);
        __builtin_amdgcn_s_setprio(0);
    }
#undef STGA
#undef STGB
#undef FRGA
#undef FRGB

    // epilogue: 4 bands of 64 rows x 128 cols via LDS fp32 staging (stride 132)
    __syncthreads();
    float* lc = (float*)sm;
    const float g = gamma[0];
#pragma unroll
    for (int h = 0; h < 4; ++h) {
        if (h) __syncthreads();
        if ((w >> 1) == h) {
#pragma unroll
            for (int mi = 0; mi < 4; ++mi)
#pragma unroll
                for (int reg = 0; reg < 4; ++reg) {
                    const int rl = mi * 16 + quad * 4 + reg;
#pragma unroll
                    for (int ni = 0; ni < 4; ++ni)
                        lc[rl * 132 + wn + ni * 16 + l15] = acc[mi][ni][reg];
                }
        }
        __syncthreads();
#pragma unroll
        for (int k = 0; k < 4; ++k) {
            const int r = (t >> 5) + k * 16;
            const int c4 = (t & 31) * 4;
            float4 v = *(float4*)&lc[r * 132 + c4];
            const int row = m0 + h * 64 + r;
            const float be = beff[b * Cn + row];
            const size_t base = ((size_t)(b * Cn + row)) * Nn + n0 + c4;
            float4 xr = *(const float4*)(xres + base);
            float4 o;
            o.x = g * (v.x + be) + xr.x;
            o.y = g * (v.y + be) + xr.y;
            o.z = g * (v.z + be) + xr.z;
            o.w = g * (v.w + be) + xr.w;
            *(float4*)(outF + base) = o;
        }
    }
}

// ---------------------------------------------------------------------------
extern "C" void kernel_launch(void* const* d_in, const int* in_sizes, int n_in,
                              void* d_out, int out_size, void* d_ws, size_t ws_size,
                              hipStream_t stream)
{
    const float* x     = (const float*)d_in[0];
    const float* y     = (const float*)d_in[1];
    const float* wq    = (const float*)d_in[2];
    const float* bq    = (const float*)d_in[3];
    const float* wk    = (const float*)d_in[4];
    const float* bk    = (const float*)d_in[5];
    const float* wv    = (const float*)d_in[6];
    const float* bv    = (const float*)d_in[7];
    const float* gamma = (const float*)d_in[8];
    float* out = (float*)d_out;

    char* ws = (char*)d_ws;
    u16*   xt   = (u16*)  (ws + 0);           // 67,108,864 B : x^T bf16 (B,N,C)
    float* sxp  = (float*)(ws + 67108864);    //  2,097,152 B : partial sums
    float* sx   = (float*)(ws + 69206016);    //     32,768 B
    float* qy   = (float*)(ws + 69238784);    //     32,768 B
    float* sk   = (float*)(ws + 69271552);    //     32,768 B
    float* beff = (float*)(ws + 69304320);    //     32,768 B
    u16*   attn = (u16*)  (ws + 69337088);    //  8,388,608 B : attn bf16
    u16*   wvt  = (u16*)  (ws + 77725696);    //    524,288 B : wv^T bf16
    u16*   weff = (u16*)  (ws + 78249984);    //  8,388,608 B : Weff bf16
    // total ~86.6 MB

    k_transpose<<<dim3(64, 4, Bn), dim3(256), 0, stream>>>(x, xt, sxp);
    k_sxred<<<dim3(32), dim3(256), 0, stream>>>(sxp, sx);
    k_wvt<<<dim3(8, 8), dim3(256), 0, stream>>>(wv, wvt);
    k_qk<<<dim3(128, Bn, 2), dim3(256), 0, stream>>>(wq, bq, wk, bk, y, sx, qy, sk);
    k_softmax<<<dim3(Bn * Cn), dim3(256), 0, stream>>>(qy, sk, bv, attn, beff);
    // Weff[b] = attn[b] @ wv  (as A * wv_t^T), output bf16
    k_gemm<0><<<dim3(4, 4, Bn), dim3(256), 0, stream>>>(
        attn, (size_t)Cn * Cn, wvt, (size_t)0, Cn,
        weff, (size_t)Cn * Cn, nullptr, nullptr, nullptr, nullptr);
    // out[b] = gamma * (Weff[b] @ x[b] + beff) + x
    // 256x128 / BK=32 / A ring-2 + B ring-5 / 2-blocks-per-CU pipelined GEMM
    if (hipFuncSetAttribute((const void*)k_gemm2,
                            hipFuncAttributeMaxDynamicSharedMemorySize,
                            73728) == hipSuccess) {
        k_gemm2<<<dim3(32, 2, Bn), dim3(512), 73728, stream>>>(
            weff, xt, out, x, beff, gamma);
    } else {
        k_gemm<1><<<dim3(32, 4, Bn), dim3(256), 0, stream>>>(
            weff, (size_t)Cn * Cn, xt, (size_t)Nn * Cn, Nn,
            nullptr, (size_t)0, out, x, beff, gamma);
    }
}

// Round 5
// 353.366 us; speedup vs baseline: 1.0137x; 1.0137x over previous
//
#include <hip/hip_runtime.h>
#include <hip/hip_bf16.h>

#define Bn 16
#define Cn 512
#define Nn 4096

typedef unsigned short u16;
typedef __bf16 bf16x8 __attribute__((ext_vector_type(8)));
typedef float f32x4 __attribute__((ext_vector_type(4)));
typedef unsigned short u16x8 __attribute__((ext_vector_type(8)));

__device__ __forceinline__ u16 f2bf(float f) {
    __hip_bfloat16 h = __float2bfloat16(f);
    return *reinterpret_cast<u16*>(&h);
}

// async global->LDS, 16B per lane; LDS dest is wave-uniform base + lane*16
__device__ __forceinline__ void glds16(const u16* g, u16* l) {
    __builtin_amdgcn_global_load_lds(
        (const __attribute__((address_space(1))) void*)g,
        (__attribute__((address_space(3))) void*)l, 16, 0, 0);
}

// ---------------------------------------------------------------------------
// K1: x (B,C,N) fp32 -> x_t (B,N,C) bf16, plus per-(b,c) partial sums over the
// 64-wide n-tile. 128c x 64n tile: 256B segments on both read and write sides.
// ---------------------------------------------------------------------------
__global__ __launch_bounds__(256) void k_transpose(
    const float* __restrict__ x, u16* __restrict__ xt, float* __restrict__ sxp)
{
    __shared__ float tile[128 * 65];
    const int b = blockIdx.z, c0 = blockIdx.y * 128, n0 = blockIdx.x * 64;
    const int t = threadIdx.x;
    const float* xb = x + ((size_t)(b * Cn + c0)) * Nn + n0;

    float part[8];
#pragma unroll
    for (int r = 0; r < 8; ++r) {
        int cl = (t >> 4) + r * 16;
        int nl = (t & 15) * 4;
        float4 v = *(const float4*)(xb + (size_t)cl * Nn + nl);
        float* tp = &tile[cl * 65 + nl];
        tp[0] = v.x; tp[1] = v.y; tp[2] = v.z; tp[3] = v.w;
        part[r] = (v.x + v.y) + (v.z + v.w);
    }
#pragma unroll
    for (int m = 1; m < 16; m <<= 1) {
#pragma unroll
        for (int r = 0; r < 8; ++r) part[r] += __shfl_xor(part[r], m);
    }
    if ((t & 15) == 0) {
#pragma unroll
        for (int r = 0; r < 8; ++r) {
            int cl = (t >> 4) + r * 16;
            sxp[(size_t)(b * Cn + c0 + cl) * 64 + blockIdx.x] = part[r];
        }
    }
    __syncthreads();
    u16* xtb = xt + ((size_t)(b * Nn + n0)) * Cn + c0;
#pragma unroll
    for (int r = 0; r < 4; ++r) {
        int nl = (t >> 4) + r * 16;
        int c8 = (t & 15) * 8;
        u16x8 hv;
#pragma unroll
        for (int i = 0; i < 8; ++i) hv[i] = f2bf(tile[(c8 + i) * 65 + nl]);
        *(u16x8*)(xtb + (size_t)nl * Cn + c8) = hv;
    }
}

// K1b: reduce 64 n-tile partials -> Sx[b*C+c]
__global__ __launch_bounds__(256) void k_sxred(
    const float* __restrict__ sxp, float* __restrict__ sx)
{
    int i = blockIdx.x * 256 + threadIdx.x;  // 0..8191
    const float4* p = (const float4*)(sxp + (size_t)i * 64);
    float s = 0.f;
#pragma unroll
    for (int j = 0; j < 16; ++j) {
        float4 v = p[j];
        s += (v.x + v.y) + (v.z + v.w);
    }
    sx[i] = s;
}

// K2: qy[b,o] = wq@y + bq ; sk[b,o] = wk@Sx + N*bk. One wave per output.
__global__ __launch_bounds__(256) void k_qk(
    const float* __restrict__ wq, const float* __restrict__ bq,
    const float* __restrict__ wk, const float* __restrict__ bk,
    const float* __restrict__ y, const float* __restrict__ sx,
    float* __restrict__ qy, float* __restrict__ sk)
{
    const int w = threadIdx.x >> 6, lane = threadIdx.x & 63;
    const int o = blockIdx.x * 4 + w;
    const int b = blockIdx.y;
    const int mode = blockIdx.z;
    const float* W = mode ? wk : wq;
    const float* vec = mode ? (sx + b * Cn) : (y + b * Cn);
    float sum = 0.f;
#pragma unroll
    for (int i = 0; i < 8; ++i) {
        int k2 = lane + i * 64;
        sum += W[(size_t)o * Cn + k2] * vec[k2];
    }
#pragma unroll
    for (int m = 1; m < 64; m <<= 1) sum += __shfl_xor(sum, m);
    if (lane == 0) {
        if (mode) sk[b * Cn + o] = sum + 4096.0f * bk[o];
        else      qy[b * Cn + o] = sum + bq[o];
    }
}

// K2b: wv_t[e,d] = bf16(wv[d,e]) via 64x64 LDS tile (coalesced both sides)
__global__ __launch_bounds__(256) void k_wvt(
    const float* __restrict__ wv, u16* __restrict__ wvt)
{
    __shared__ float tl[64 * 65];
    const int d0 = blockIdx.x * 64, e0 = blockIdx.y * 64;
    const int t = threadIdx.x;
#pragma unroll
    for (int r = 0; r < 4; ++r) {
        int d = (t >> 4) + r * 16, e4 = (t & 15) * 4;
        float4 v = *(const float4*)(wv + (size_t)(d0 + d) * Cn + e0 + e4);
        float* p = &tl[d * 65 + e4];
        p[0] = v.x; p[1] = v.y; p[2] = v.z; p[3] = v.w;
    }
    __syncthreads();
#pragma unroll
    for (int r = 0; r < 4; ++r) {
        int e = (t >> 4) + r * 16, d4 = (t & 15) * 4;
        ushort4 h;
        h.x = f2bf(tl[(d4 + 0) * 65 + e]);
        h.y = f2bf(tl[(d4 + 1) * 65 + e]);
        h.z = f2bf(tl[(d4 + 2) * 65 + e]);
        h.w = f2bf(tl[(d4 + 3) * 65 + e]);
        *(ushort4*)(wvt + (size_t)(e0 + e) * Cn + d0 + d4) = h;
    }
}

// K3: per (b,c) row: softmax_d(qy*sk) -> attn (bf16),
// beff = gamma * (attn . bv)   (gamma pre-folded so the final GEMM epilogue
// is a pure add; k_gemm<0> likewise folds gamma into weff)
__global__ __launch_bounds__(256) void k_softmax(
    const float* __restrict__ qy, const float* __restrict__ sk,
    const float* __restrict__ bv, u16* __restrict__ attn,
    float* __restrict__ beff, const float* __restrict__ gamma)
{
    __shared__ float red[4], red2[4], red3[4];
    const int b = blockIdx.x >> 9, c = blockIdx.x & 511;
    const int t = threadIdx.x;
    const float q = qy[b * Cn + c];
    const float l0 = q * sk[b * Cn + t];
    const float l1 = q * sk[b * Cn + t + 256];
    float mx = fmaxf(l0, l1);
#pragma unroll
    for (int m = 1; m < 64; m <<= 1) mx = fmaxf(mx, __shfl_xor(mx, m));
    if ((t & 63) == 0) red[t >> 6] = mx;
    __syncthreads();
    mx = fmaxf(fmaxf(red[0], red[1]), fmaxf(red[2], red[3]));
    const float e0 = __expf(l0 - mx), e1 = __expf(l1 - mx);
    float s = e0 + e1;
#pragma unroll
    for (int m = 1; m < 64; m <<= 1) s += __shfl_xor(s, m);
    if ((t & 63) == 0) red2[t >> 6] = s;
    __syncthreads();
    s = red2[0] + red2[1] + red2[2] + red2[3];
    const float inv = 1.0f / s;
    const float a0 = e0 * inv, a1 = e1 * inv;
    u16* arow = attn + ((size_t)(b * Cn + c)) * Cn;
    arow[t] = f2bf(a0);
    arow[t + 256] = f2bf(a1);
    float pb = a0 * bv[t] + a1 * bv[t + 256];
#pragma unroll
    for (int m = 1; m < 64; m <<= 1) pb += __shfl_xor(pb, m);
    if ((t & 63) == 0) red3[t >> 6] = pb;
    __syncthreads();
    if (t == 0)
        beff[b * Cn + c] = gamma[0] * (red3[0] + red3[1] + red3[2] + red3[3]);
}

// ---------------------------------------------------------------------------
// Shared MFMA GEMM (old 128x128 structure) — used for Weff' = gamma*(attn@wv)
// (FINAL=0, gamma folded into the bf16 output), and as fallback for the final
// GEMM (FINAL=1: out = acc + beff' + xres, with weff/beff pre-scaled).
// ---------------------------------------------------------------------------
template <int FINAL>
__global__ __launch_bounds__(256) void k_gemm(
    const u16* __restrict__ A, size_t strideA,
    const u16* __restrict__ Bt, size_t strideB,
    int N,
    u16* __restrict__ outBf, size_t strideOb,
    float* __restrict__ outF,
    const float* __restrict__ xres,
    const float* __restrict__ beff,
    const float* __restrict__ gamma)
{
    constexpr int K = 512;
    __shared__ float smem_f[8448];          // 33,792 B: K-loop 32KB / epi 33KB
    u16* la = (u16*)smem_f;                 // [128*64] bf16
    u16* lb = la + 128 * 64;
    const int b = blockIdx.z;
    const int m0 = blockIdx.y * 128;
    const int n0 = blockIdx.x * 128;
    A  += (size_t)b * strideA;
    Bt += (size_t)b * strideB;
    const int t = threadIdx.x;
    const int lane = t & 63;
    const int w = t >> 6;
    const int wm = (w >> 1) * 64, wn = (w & 1) * 64;
    const int l15 = lane & 15, quad = lane >> 4;

    f32x4 acc[4][4];
#pragma unroll
    for (int i = 0; i < 4; ++i)
#pragma unroll
        for (int j = 0; j < 4; ++j)
            acc[i][j] = (f32x4){0.f, 0.f, 0.f, 0.f};

    const int srow8 = lane >> 3;                 // 0..7
    const int lgcol = ((lane & 7) ^ srow8) * 8;  // logical k-col (swizzled)

    for (int k0 = 0; k0 < K; k0 += 64) {
        __syncthreads();
#pragma unroll
        for (int j = 0; j < 4; ++j) {
            const int row = w * 32 + j * 8 + srow8;
            const int sb = (w * 256 + j * 64) * 8;   // u16 offset of slot base
            glds16(A  + (size_t)(m0 + row) * K + k0 + lgcol, la + sb);
            glds16(Bt + (size_t)(n0 + row) * K + k0 + lgcol, lb + sb);
        }
        __syncthreads();

#pragma unroll
        for (int kk2 = 0; kk2 < 2; ++kk2) {
            bf16x8 af[4], bfr[4];
#pragma unroll
            for (int mi = 0; mi < 4; ++mi) {
                const int r = wm + mi * 16 + l15;
                const int pg = ((kk2 << 2) + quad) ^ (l15 & 7);
                af[mi] = *(const bf16x8*)&la[r * 64 + pg * 8];
            }
#pragma unroll
            for (int ni = 0; ni < 4; ++ni) {
                const int r = wn + ni * 16 + l15;
                const int pg = ((kk2 << 2) + quad) ^ (l15 & 7);
                bfr[ni] = *(const bf16x8*)&lb[r * 64 + pg * 8];
            }
#pragma unroll
            for (int mi = 0; mi < 4; ++mi)
#pragma unroll
                for (int ni = 0; ni < 4; ++ni)
                    acc[mi][ni] = __builtin_amdgcn_mfma_f32_16x16x32_bf16(
                        af[mi], bfr[ni], acc[mi][ni], 0, 0, 0);
        }
    }

    if (FINAL) {
        // fallback path: weff/beff pre-scaled by gamma -> pure adds here
        float* lc = smem_f;                  // 64 rows x stride 132 fp32
#pragma unroll
        for (int h = 0; h < 2; ++h) {
            __syncthreads();
            if ((w >> 1) == h) {
#pragma unroll
                for (int mi = 0; mi < 4; ++mi)
#pragma unroll
                    for (int reg = 0; reg < 4; ++reg) {
                        const int rl = mi * 16 + quad * 4 + reg;
#pragma unroll
                        for (int ni = 0; ni < 4; ++ni)
                            lc[rl * 132 + wn + ni * 16 + l15] = acc[mi][ni][reg];
                    }
            }
            __syncthreads();
            const int rb = h * 64;
#pragma unroll
            for (int rr = 0; rr < 8; ++rr) {
                const int rl = rr * 8 + (t >> 5);
                const int c4 = (t & 31) * 4;
                float4 v = *(float4*)&lc[rl * 132 + c4];
                const int r = m0 + rb + rl;
                const float be = beff[b * Cn + r];
                const size_t base = ((size_t)(b * Cn + r)) * N + n0 + c4;
                float4 xr = *(const float4*)(xres + base);
                float4 o;
                o.x = (v.x + be) + xr.x;
                o.y = (v.y + be) + xr.y;
                o.z = (v.z + be) + xr.z;
                o.w = (v.w + be) + xr.w;
                *(float4*)(outF + base) = o;
            }
        }
    } else {
        const float gs = gamma[0];           // fold gamma into weff bf16
#pragma unroll
        for (int mi = 0; mi < 4; ++mi) {
#pragma unroll
            for (int reg = 0; reg < 4; ++reg) {
                const int r = m0 + wm + mi * 16 + quad * 4 + reg;
                const size_t base = (size_t)b * strideOb + (size_t)r * N;
#pragma unroll
                for (int ni = 0; ni < 4; ++ni) {
                    const int cidx = n0 + wn + ni * 16 + l15;
                    outBf[base + cidx] = f2bf(gs * acc[mi][ni][reg]);
                }
            }
        }
    }
}

// ---------------------------------------------------------------------------
// k_gemm2 (round 5 = round 4 resubmit): final GEMM out = Weff'@xt + beff' + x,
// Weff'/beff' carry gamma (folded upstream). Round-2 structure (256x128 tile,
// BK=32, 8 waves 4Mx2N, ring-3 x 24KB LDS, 2 blocks/CU) with ONE change:
// the residual x enters through the MFMA C-operand — acc is initialized from
// xres (fp32, exact) before the K-loop. The 134MB xres read issues at block
// start and drains under the prologue + first K-tiles; the epilogue becomes
// WRITE-ONLY (fixes the HBM phase-burst that capped rounds 1-3 at ~50% duty
// cycle). vmcnt ledger: the 16 scalar xres loads are oldest in the queue;
// tile-0's vmcnt(3) retires them, steady-state ledger unchanged.
// ---------------------------------------------------------------------------
__global__ __launch_bounds__(512, 4) void k_gemm2(
    const u16* __restrict__ A,    // weff' = gamma*(attn@wv) (B,512,512) bf16
    const u16* __restrict__ Bt,   // xt   (B,4096,512) bf16
    float* __restrict__ outF,
    const float* __restrict__ xres,
    const float* __restrict__ beff)   // pre-scaled by gamma
{
    extern __shared__ u16 sm[];               // 73728 B = 3 slots x 24 KiB
    const int b = blockIdx.z;
    const int m0 = blockIdx.y << 8;           // 256-row panel
    const int n0 = blockIdx.x << 7;           // 128-col panel
    const int t = threadIdx.x;
    const int lane = t & 63, w = t >> 6;
    const int wm = (w >> 1) << 6, wn = (w & 1) << 6;
    const int l15 = lane & 15, quad = lane >> 4;

    const u16* Ag = A + (size_t)b * Cn * Cn;
    const u16* Bg = Bt + (size_t)b * ((size_t)Nn * Cn);
    // staging: thread t covers LDS u16 [t*8 .. t*8+8) of its chunk;
    // row = t>>2 (within chunk), phys group t&3 holds logical group
    // (t&3)^((row>>1)&3) -> pre-swizzled global column.
    const int srow = t >> 2;
    const int scol = (((t & 3) ^ ((srow >> 1) & 3))) << 3;
    const u16* pa = Ag + (size_t)(m0 + srow) * Cn + scol;
    const u16* pb = Bg + (size_t)(n0 + srow) * Cn + scol;
    u16* dw = sm + w * 512;                   // wave-uniform dest base

#define SLOTO(s) ((s) * 12288)
#define STGA(s, c, k0) \
    glds16(pa + (size_t)(c) * (128 * Cn) + (k0), dw + SLOTO(s) + (c) * 4096)
#define STGB(s, k0) glds16(pb + (k0), dw + SLOTO(s) + 8192)
#define FRG(base, row, qd) \
    (*(const bf16x8*)&sm[(base) + (row) * 32 + \
                         (((qd) ^ (((row) >> 1) & 3)) << 3)])

    // acc init = residual x (exact fp32). 16 dword loads/thread, issued
    // FIRST (oldest in vmcnt queue). Consumed by the tile-0 MFMA, whose
    // wait is covered by the vmcnt(3) below.
    f32x4 acc[4][4];
#pragma unroll
    for (int mi = 0; mi < 4; ++mi)
#pragma unroll
        for (int reg = 0; reg < 4; ++reg) {
            const int row = m0 + wm + mi * 16 + quad * 4 + reg;
            const float* xr =
                xres + ((size_t)(b * Cn + row)) * Nn + n0 + wn + l15;
#pragma unroll
            for (int ni = 0; ni < 4; ++ni)
                acc[mi][ni][reg] = xr[ni * 16];
        }
    // pin issue order: all xres loads precede the glds16 stream so the
    // hand vmcnt ledger below stays exact (memory clobber for the compiler's
    // memory model + sched_barrier(0) so the scheduler can't move anything
    // across either — rule #18).
    asm volatile("" ::: "memory");
    __builtin_amdgcn_sched_barrier(0);

    // prologue: stage tiles 0 and 1 (6 loads/wave outstanding after xres)
    STGA(0, 0, 0); STGA(0, 1, 0); STGB(0, 0);
    STGA(1, 0, 32); STGA(1, 1, 32); STGB(1, 32);

#pragma unroll
    for (int tI = 0; tI < 16; ++tI) {
        // entering tile tI: outstanding = [xres if tI==0] tiles {tI, tI+1}.
        // vmcnt(3) forces xres + tile tI complete, leaves tI+1's 3 in flight.
        if (tI < 15) { asm volatile("s_waitcnt vmcnt(3)" ::: "memory"); }
        else         { asm volatile("s_waitcnt vmcnt(0)" ::: "memory"); }
        __builtin_amdgcn_s_barrier();   // tile tI visible to all waves; all
                                        // waves done reading tile tI-1
        if (tI <= 13) {                 // stage tile tI+2 into slot (tI+2)%3
            const int s2 = (tI + 2) % 3;
            const int k2 = (tI + 2) << 5;
            STGA(s2, 0, k2); STGA(s2, 1, k2); STGB(s2, k2);
        }
        const int sb = SLOTO(tI % 3);
        bf16x8 af[4], bf[4];
#pragma unroll
        for (int mi = 0; mi < 4; ++mi)
            af[mi] = FRG(sb, wm + mi * 16 + l15, quad);
#pragma unroll
        for (int ni = 0; ni < 4; ++ni)
            bf[ni] = FRG(sb + 8192, wn + ni * 16 + l15, quad);
        __builtin_amdgcn_s_setprio(1);
#pragma unroll
        for (int mi = 0; mi < 4; ++mi)
#pragma unroll
            for (int ni = 0; ni < 4; ++ni)
                acc[mi][ni] = __builtin_amdgcn_mfma_f32_16x16x32_bf16(
                    af[mi], bf[ni], acc[mi][ni], 0, 0, 0);
        __builtin_amdgcn_s_setprio(0);
    }
#undef STGA
#undef STGB
#undef FRG
#undef SLOTO

    // epilogue (WRITE-ONLY): 4 bands of 64 rows x 128 cols via LDS fp32
    // staging (stride 132) for coalesced 512B row stores.
    __syncthreads();
    float* lc = (float*)sm;
#pragma unroll
    for (int h = 0; h < 4; ++h) {
        if (h) __syncthreads();
        if ((w >> 1) == h) {
#pragma unroll
            for (int mi = 0; mi < 4; ++mi)
#pragma unroll
                for (int reg = 0; reg < 4; ++reg) {
                    const int rl = mi * 16 + quad * 4 + reg;
#pragma unroll
                    for (int ni = 0; ni < 4; ++ni)
                        lc[rl * 132 + wn + ni * 16 + l15] = acc[mi][ni][reg];
                }
        }
        __syncthreads();
#pragma unroll
        for (int k = 0; k < 4; ++k) {
            const int r = (t >> 5) + k * 16;
            const int c4 = (t & 31) * 4;
            float4 v = *(float4*)&lc[r * 132 + c4];
            const int row = m0 + h * 64 + r;
            const float be = beff[b * Cn + row];
            const size_t base = ((size_t)(b * Cn + row)) * Nn + n0 + c4;
            float4 o;
            o.x = v.x + be;
            o.y = v.y + be;
            o.z = v.z + be;
            o.w = v.w + be;
            *(float4*)(outF + base) = o;
        }
    }
}

// ---------------------------------------------------------------------------
extern "C" void kernel_launch(void* const* d_in, const int* in_sizes, int n_in,
                              void* d_out, int out_size, void* d_ws, size_t ws_size,
                              hipStream_t stream)
{
    const float* x     = (const float*)d_in[0];
    const float* y     = (const float*)d_in[1];
    const float* wq    = (const float*)d_in[2];
    const float* bq    = (const float*)d_in[3];
    const float* wk    = (const float*)d_in[4];
    const float* bk    = (const float*)d_in[5];
    const float* wv    = (const float*)d_in[6];
    const float* bv    = (const float*)d_in[7];
    const float* gamma = (const float*)d_in[8];
    float* out = (float*)d_out;

    char* ws = (char*)d_ws;
    u16*   xt   = (u16*)  (ws + 0);           // 67,108,864 B : x^T bf16 (B,N,C)
    float* sxp  = (float*)(ws + 67108864);    //  2,097,152 B : partial sums
    float* sx   = (float*)(ws + 69206016);    //     32,768 B
    float* qy   = (float*)(ws + 69238784);    //     32,768 B
    float* sk   = (float*)(ws + 69271552);    //     32,768 B
    float* beff = (float*)(ws + 69304320);    //     32,768 B
    u16*   attn = (u16*)  (ws + 69337088);    //  8,388,608 B : attn bf16
    u16*   wvt  = (u16*)  (ws + 77725696);    //    524,288 B : wv^T bf16
    u16*   weff = (u16*)  (ws + 78249984);    //  8,388,608 B : Weff' bf16
    // total ~86.6 MB

    k_transpose<<<dim3(64, 4, Bn), dim3(256), 0, stream>>>(x, xt, sxp);
    k_sxred<<<dim3(32), dim3(256), 0, stream>>>(sxp, sx);
    k_wvt<<<dim3(8, 8), dim3(256), 0, stream>>>(wv, wvt);
    k_qk<<<dim3(128, Bn, 2), dim3(256), 0, stream>>>(wq, bq, wk, bk, y, sx, qy, sk);
    k_softmax<<<dim3(Bn * Cn), dim3(256), 0, stream>>>(qy, sk, bv, attn, beff, gamma);
    // Weff'[b] = gamma * (attn[b] @ wv)  (as A * wv_t^T), output bf16
    k_gemm<0><<<dim3(4, 4, Bn), dim3(256), 0, stream>>>(
        attn, (size_t)Cn * Cn, wvt, (size_t)0, Cn,
        weff, (size_t)Cn * Cn, nullptr, nullptr, nullptr, gamma);
    // out[b] = Weff'[b] @ x[b] + beff' + x  (residual via MFMA C-init)
    if (hipFuncSetAttribute((const void*)k_gemm2,
                            hipFuncAttributeMaxDynamicSharedMemorySize,
                            73728) == hipSuccess) {
        k_gemm2<<<dim3(32, 2, Bn), dim3(512), 73728, stream>>>(
            weff, xt, out, x, beff);
    } else {
        k_gemm<1><<<dim3(32, 4, Bn), dim3(256), 0, stream>>>(
            weff, (size_t)Cn * Cn, xt, (size_t)Nn * Cn, Nn,
            nullptr, (size_t)0, out, x, beff, gamma);
    }
}

// Round 7
// 331.617 us; speedup vs baseline: 1.0801x; 1.0656x over previous
//
#include <hip/hip_runtime.h>
#include <hip/hip_bf16.h>

#define Bn 16
#define Cn 512
#define Nn 4096

typedef unsigned short u16;
typedef __bf16 bf16x8 __attribute__((ext_vector_type(8)));
typedef float f32x4 __attribute__((ext_vector_type(4)));
typedef unsigned short u16x8 __attribute__((ext_vector_type(8)));

__device__ __forceinline__ u16 f2bf(float f) {
    __hip_bfloat16 h = __float2bfloat16(f);
    return *reinterpret_cast<u16*>(&h);
}

// async global->LDS, 16B per lane; LDS dest is wave-uniform base + lane*16
__device__ __forceinline__ void glds16(const u16* g, u16* l) {
    __builtin_amdgcn_global_load_lds(
        (const __attribute__((address_space(1))) void*)g,
        (__attribute__((address_space(3))) void*)l, 16, 0, 0);
}

// ---------------------------------------------------------------------------
// K1: x (B,C,N) fp32 -> x_t (B,N,C) bf16, plus per-(b,c) partial sums over the
// 64-wide n-tile. 128c x 64n tile: 256B segments on both read and write sides.
// ---------------------------------------------------------------------------
__global__ __launch_bounds__(256) void k_transpose(
    const float* __restrict__ x, u16* __restrict__ xt, float* __restrict__ sxp)
{
    __shared__ float tile[128 * 65];
    const int b = blockIdx.z, c0 = blockIdx.y * 128, n0 = blockIdx.x * 64;
    const int t = threadIdx.x;
    const float* xb = x + ((size_t)(b * Cn + c0)) * Nn + n0;

    float part[8];
#pragma unroll
    for (int r = 0; r < 8; ++r) {
        int cl = (t >> 4) + r * 16;
        int nl = (t & 15) * 4;
        float4 v = *(const float4*)(xb + (size_t)cl * Nn + nl);
        float* tp = &tile[cl * 65 + nl];
        tp[0] = v.x; tp[1] = v.y; tp[2] = v.z; tp[3] = v.w;
        part[r] = (v.x + v.y) + (v.z + v.w);
    }
#pragma unroll
    for (int m = 1; m < 16; m <<= 1) {
#pragma unroll
        for (int r = 0; r < 8; ++r) part[r] += __shfl_xor(part[r], m);
    }
    if ((t & 15) == 0) {
#pragma unroll
        for (int r = 0; r < 8; ++r) {
            int cl = (t >> 4) + r * 16;
            sxp[(size_t)(b * Cn + c0 + cl) * 64 + blockIdx.x] = part[r];
        }
    }
    __syncthreads();
    u16* xtb = xt + ((size_t)(b * Nn + n0)) * Cn + c0;
#pragma unroll
    for (int r = 0; r < 4; ++r) {
        int nl = (t >> 4) + r * 16;
        int c8 = (t & 15) * 8;
        u16x8 hv;
#pragma unroll
        for (int i = 0; i < 8; ++i) hv[i] = f2bf(tile[(c8 + i) * 65 + nl]);
        *(u16x8*)(xtb + (size_t)nl * Cn + c8) = hv;
    }
}

// K1b: reduce 64 n-tile partials -> Sx[b*C+c]
__global__ __launch_bounds__(256) void k_sxred(
    const float* __restrict__ sxp, float* __restrict__ sx)
{
    int i = blockIdx.x * 256 + threadIdx.x;  // 0..8191
    const float4* p = (const float4*)(sxp + (size_t)i * 64);
    float s = 0.f;
#pragma unroll
    for (int j = 0; j < 16; ++j) {
        float4 v = p[j];
        s += (v.x + v.y) + (v.z + v.w);
    }
    sx[i] = s;
}

// K2: qy[b,o] = wq@y + bq ; sk[b,o] = wk@Sx + N*bk. One wave per output.
__global__ __launch_bounds__(256) void k_qk(
    const float* __restrict__ wq, const float* __restrict__ bq,
    const float* __restrict__ wk, const float* __restrict__ bk,
    const float* __restrict__ y, const float* __restrict__ sx,
    float* __restrict__ qy, float* __restrict__ sk)
{
    const int w = threadIdx.x >> 6, lane = threadIdx.x & 63;
    const int o = blockIdx.x * 4 + w;
    const int b = blockIdx.y;
    const int mode = blockIdx.z;
    const float* W = mode ? wk : wq;
    const float* vec = mode ? (sx + b * Cn) : (y + b * Cn);
    float sum = 0.f;
#pragma unroll
    for (int i = 0; i < 8; ++i) {
        int k2 = lane + i * 64;
        sum += W[(size_t)o * Cn + k2] * vec[k2];
    }
#pragma unroll
    for (int m = 1; m < 64; m <<= 1) sum += __shfl_xor(sum, m);
    if (lane == 0) {
        if (mode) sk[b * Cn + o] = sum + 4096.0f * bk[o];
        else      qy[b * Cn + o] = sum + bq[o];
    }
}

// K2b: wv_t[e,d] = bf16(wv[d,e]) via 64x64 LDS tile (coalesced both sides)
__global__ __launch_bounds__(256) void k_wvt(
    const float* __restrict__ wv, u16* __restrict__ wvt)
{
    __shared__ float tl[64 * 65];
    const int d0 = blockIdx.x * 64, e0 = blockIdx.y * 64;
    const int t = threadIdx.x;
#pragma unroll
    for (int r = 0; r < 4; ++r) {
        int d = (t >> 4) + r * 16, e4 = (t & 15) * 4;
        float4 v = *(const float4*)(wv + (size_t)(d0 + d) * Cn + e0 + e4);
        float* p = &tl[d * 65 + e4];
        p[0] = v.x; p[1] = v.y; p[2] = v.z; p[3] = v.w;
    }
    __syncthreads();
#pragma unroll
    for (int r = 0; r < 4; ++r) {
        int e = (t >> 4) + r * 16, d4 = (t & 15) * 4;
        ushort4 h;
        h.x = f2bf(tl[(d4 + 0) * 65 + e]);
        h.y = f2bf(tl[(d4 + 1) * 65 + e]);
        h.z = f2bf(tl[(d4 + 2) * 65 + e]);
        h.w = f2bf(tl[(d4 + 3) * 65 + e]);
        *(ushort4*)(wvt + (size_t)(e0 + e) * Cn + d0 + d4) = h;
    }
}

// K3: per (b,c) row: softmax_d(qy*sk) -> attn (bf16),
// beff = gamma * (attn . bv)   (gamma pre-folded so the final GEMM epilogue
// is a pure add; k_gemm<0> likewise folds gamma into weff)
__global__ __launch_bounds__(256) void k_softmax(
    const float* __restrict__ qy, const float* __restrict__ sk,
    const float* __restrict__ bv, u16* __restrict__ attn,
    float* __restrict__ beff, const float* __restrict__ gamma)
{
    __shared__ float red[4], red2[4], red3[4];
    const int b = blockIdx.x >> 9, c = blockIdx.x & 511;
    const int t = threadIdx.x;
    const float q = qy[b * Cn + c];
    const float l0 = q * sk[b * Cn + t];
    const float l1 = q * sk[b * Cn + t + 256];
    float mx = fmaxf(l0, l1);
#pragma unroll
    for (int m = 1; m < 64; m <<= 1) mx = fmaxf(mx, __shfl_xor(mx, m));
    if ((t & 63) == 0) red[t >> 6] = mx;
    __syncthreads();
    mx = fmaxf(fmaxf(red[0], red[1]), fmaxf(red[2], red[3]));
    const float e0 = __expf(l0 - mx), e1 = __expf(l1 - mx);
    float s = e0 + e1;
#pragma unroll
    for (int m = 1; m < 64; m <<= 1) s += __shfl_xor(s, m);
    if ((t & 63) == 0) red2[t >> 6] = s;
    __syncthreads();
    s = red2[0] + red2[1] + red2[2] + red2[3];
    const float inv = 1.0f / s;
    const float a0 = e0 * inv, a1 = e1 * inv;
    u16* arow = attn + ((size_t)(b * Cn + c)) * Cn;
    arow[t] = f2bf(a0);
    arow[t + 256] = f2bf(a1);
    float pb = a0 * bv[t] + a1 * bv[t + 256];
#pragma unroll
    for (int m = 1; m < 64; m <<= 1) pb += __shfl_xor(pb, m);
    if ((t & 63) == 0) red3[t >> 6] = pb;
    __syncthreads();
    if (t == 0)
        beff[b * Cn + c] = gamma[0] * (red3[0] + red3[1] + red3[2] + red3[3]);
}

// ---------------------------------------------------------------------------
// Shared MFMA GEMM (old 128x128 structure) — used for Weff' = gamma*(attn@wv)
// (FINAL=0, gamma folded into the bf16 output), and as fallback for the final
// GEMM (FINAL=1: out = acc + beff' + xres, with weff/beff pre-scaled).
// ---------------------------------------------------------------------------
template <int FINAL>
__global__ __launch_bounds__(256) void k_gemm(
    const u16* __restrict__ A, size_t strideA,
    const u16* __restrict__ Bt, size_t strideB,
    int N,
    u16* __restrict__ outBf, size_t strideOb,
    float* __restrict__ outF,
    const float* __restrict__ xres,
    const float* __restrict__ beff,
    const float* __restrict__ gamma)
{
    constexpr int K = 512;
    __shared__ float smem_f[8448];          // 33,792 B: K-loop 32KB / epi 33KB
    u16* la = (u16*)smem_f;                 // [128*64] bf16
    u16* lb = la + 128 * 64;
    const int b = blockIdx.z;
    const int m0 = blockIdx.y * 128;
    const int n0 = blockIdx.x * 128;
    A  += (size_t)b * strideA;
    Bt += (size_t)b * strideB;
    const int t = threadIdx.x;
    const int lane = t & 63;
    const int w = t >> 6;
    const int wm = (w >> 1) * 64, wn = (w & 1) * 64;
    const int l15 = lane & 15, quad = lane >> 4;

    f32x4 acc[4][4];
#pragma unroll
    for (int i = 0; i < 4; ++i)
#pragma unroll
        for (int j = 0; j < 4; ++j)
            acc[i][j] = (f32x4){0.f, 0.f, 0.f, 0.f};

    const int srow8 = lane >> 3;                 // 0..7
    const int lgcol = ((lane & 7) ^ srow8) * 8;  // logical k-col (swizzled)

    for (int k0 = 0; k0 < K; k0 += 64) {
        __syncthreads();
#pragma unroll
        for (int j = 0; j < 4; ++j) {
            const int row = w * 32 + j * 8 + srow8;
            const int sb = (w * 256 + j * 64) * 8;   // u16 offset of slot base
            glds16(A  + (size_t)(m0 + row) * K + k0 + lgcol, la + sb);
            glds16(Bt + (size_t)(n0 + row) * K + k0 + lgcol, lb + sb);
        }
        __syncthreads();

#pragma unroll
        for (int kk2 = 0; kk2 < 2; ++kk2) {
            bf16x8 af[4], bfr[4];
#pragma unroll
            for (int mi = 0; mi < 4; ++mi) {
                const int r = wm + mi * 16 + l15;
                const int pg = ((kk2 << 2) + quad) ^ (l15 & 7);
                af[mi] = *(const bf16x8*)&la[r * 64 + pg * 8];
            }
#pragma unroll
            for (int ni = 0; ni < 4; ++ni) {
                const int r = wn + ni * 16 + l15;
                const int pg = ((kk2 << 2) + quad) ^ (l15 & 7);
                bfr[ni] = *(const bf16x8*)&lb[r * 64 + pg * 8];
            }
#pragma unroll
            for (int mi = 0; mi < 4; ++mi)
#pragma unroll
                for (int ni = 0; ni < 4; ++ni)
                    acc[mi][ni] = __builtin_amdgcn_mfma_f32_16x16x32_bf16(
                        af[mi], bfr[ni], acc[mi][ni], 0, 0, 0);
        }
    }

    if (FINAL) {
        // fallback path: weff/beff pre-scaled by gamma -> pure adds here
        float* lc = smem_f;                  // 64 rows x stride 132 fp32
#pragma unroll
        for (int h = 0; h < 2; ++h) {
            __syncthreads();
            if ((w >> 1) == h) {
#pragma unroll
                for (int mi = 0; mi < 4; ++mi)
#pragma unroll
                    for (int reg = 0; reg < 4; ++reg) {
                        const int rl = mi * 16 + quad * 4 + reg;
#pragma unroll
                        for (int ni = 0; ni < 4; ++ni)
                            lc[rl * 132 + wn + ni * 16 + l15] = acc[mi][ni][reg];
                    }
            }
            __syncthreads();
            const int rb = h * 64;
#pragma unroll
            for (int rr = 0; rr < 8; ++rr) {
                const int rl = rr * 8 + (t >> 5);
                const int c4 = (t & 31) * 4;
                float4 v = *(float4*)&lc[rl * 132 + c4];
                const int r = m0 + rb + rl;
                const float be = beff[b * Cn + r];
                const size_t base = ((size_t)(b * Cn + r)) * N + n0 + c4;
                float4 xr = *(const float4*)(xres + base);
                float4 o;
                o.x = (v.x + be) + xr.x;
                o.y = (v.y + be) + xr.y;
                o.z = (v.z + be) + xr.z;
                o.w = (v.w + be) + xr.w;
                *(float4*)(outF + base) = o;
            }
        }
    } else {
        const float gs = gamma[0];           // fold gamma into weff bf16
#pragma unroll
        for (int mi = 0; mi < 4; ++mi) {
#pragma unroll
            for (int reg = 0; reg < 4; ++reg) {
                const int r = m0 + wm + mi * 16 + quad * 4 + reg;
                const size_t base = (size_t)b * strideOb + (size_t)r * N;
#pragma unroll
                for (int ni = 0; ni < 4; ++ni) {
                    const int cidx = n0 + wn + ni * 16 + l15;
                    outBf[base + cidx] = f2bf(gs * acc[mi][ni][reg]);
                }
            }
        }
    }
}

// ---------------------------------------------------------------------------
// k_gemm2 (round 7 = round 6 with the nontemporal-store type fixed): final
// GEMM out = Weff'@xt + beff' + x (gamma folded upstream; residual via MFMA
// C-init, write-only epilogue). Asymmetric ring DEPTHS:
//   A (weff, L2-hot):   ring-3 x 16KB, stage A(tI+2)  (cover ~2 phases)
//   B (xt, L3 stream):  ring-4 x 8KB,  stage B(tI+3)  (cover ~3 phases ~1000cy)
// LDS = 48K + 32K = 80KB -> still 2 blocks/CU (160KB). Removes the per-tile
// residual vmcnt stall that kept the K-loop ~80% stalled (HBM idle during it).
// Ledger: prologue B0,A0,A0,B1,A1,A1,B2; steady queue entering tile tI =
// B(tI),A(tI)x2,B(tI+1),A(tI+1)x2,B(tI+2) -> wait vmcnt(4) forces B/A(tI);
// tail: vmcnt(3) @14, vmcnt(0) @15. Write slots (tI+2)%3 / (tI+3)%4 are
// disjoint from read slots tI%3 / tI%4. Output uses nontemporal stores
// (out never re-read; keeps x/xt resident in L3).
// ---------------------------------------------------------------------------
__global__ __launch_bounds__(512, 4) void k_gemm2(
    const u16* __restrict__ A,    // weff' = gamma*(attn@wv) (B,512,512) bf16
    const u16* __restrict__ Bt,   // xt   (B,4096,512) bf16
    float* __restrict__ outF,
    const float* __restrict__ xres,
    const float* __restrict__ beff)   // pre-scaled by gamma
{
    extern __shared__ u16 sm[];   // 81920 B = A ring-3 x 16KB + B ring-4 x 8KB
    const int b = blockIdx.z;
    const int m0 = blockIdx.y << 8;           // 256-row panel
    const int n0 = blockIdx.x << 7;           // 128-col panel
    const int t = threadIdx.x;
    const int lane = t & 63, w = t >> 6;
    const int wm = (w >> 1) << 6, wn = (w & 1) << 6;
    const int l15 = lane & 15, quad = lane >> 4;

    const u16* Ag = A + (size_t)b * Cn * Cn;
    const u16* Bg = Bt + (size_t)b * ((size_t)Nn * Cn);
    // staging: thread t covers LDS u16 [t*8 .. t*8+8) of its chunk;
    // row = t>>2 (within chunk), phys group t&3 holds logical group
    // (t&3)^((row>>1)&3) -> pre-swizzled global column.
    const int srow = t >> 2;
    const int scol = (((t & 3) ^ ((srow >> 1) & 3))) << 3;
    const u16* pa = Ag + (size_t)(m0 + srow) * Cn + scol;
    const u16* pb = Bg + (size_t)(n0 + srow) * Cn + scol;
    const int dwo = w * 512;                  // wave-uniform dest base (u16)

    // A slot s(0..2): u16 off s*8192 (+ chunk c*4096). B slot s(0..3):
    // u16 off 24576 + s*4096.
#define STGA(s, c, k0) \
    glds16(pa + (size_t)(c) * (128 * Cn) + (k0), \
           sm + (s) * 8192 + (c) * 4096 + dwo)
#define STGB(s, k0) glds16(pb + (k0), sm + 24576 + (s) * 4096 + dwo)
#define FRGA(s, row, qd) \
    (*(const bf16x8*)&sm[(s) * 8192 + (row) * 32 + \
                         (((qd) ^ (((row) >> 1) & 3)) << 3)])
#define FRGB(s, row, qd) \
    (*(const bf16x8*)&sm[24576 + (s) * 4096 + (row) * 32 + \
                         (((qd) ^ (((row) >> 1) & 3)) << 3)])

    // acc init = residual x (exact fp32). 64 dword loads/thread, issued
    // FIRST (oldest in vmcnt queue); retired by tile-0's vmcnt(4).
    f32x4 acc[4][4];
#pragma unroll
    for (int mi = 0; mi < 4; ++mi)
#pragma unroll
        for (int reg = 0; reg < 4; ++reg) {
            const int row = m0 + wm + mi * 16 + quad * 4 + reg;
            const float* xr =
                xres + ((size_t)(b * Cn + row)) * Nn + n0 + wn + l15;
#pragma unroll
            for (int ni = 0; ni < 4; ++ni)
                acc[mi][ni][reg] = xr[ni * 16];
        }
    // pin issue order: xres loads precede the glds16 stream (rule #18).
    asm volatile("" ::: "memory");
    __builtin_amdgcn_sched_barrier(0);

    // prologue: interleaved so the queue matches the steady-state pattern:
    // B(0), A(0)x2, B(1), A(1)x2, B(2)
    STGB(0, 0);
    STGA(0, 0, 0); STGA(0, 1, 0);
    STGB(1, 32);
    STGA(1, 0, 32); STGA(1, 1, 32);
    STGB(2, 64);

#pragma unroll
    for (int tI = 0; tI < 16; ++tI) {
        // entering tile tI, queue (oldest->newest):
        //   B(tI), A(tI)x2, B(tI+1), A(tI+1)x2, B(tI+2)
        // vmcnt(4) forces B(tI)+A(tI)x2 (and, at tI=0, the xres loads),
        // leaving B(tI+1), A(tI+1)x2, B(tI+2) in flight.
        if (tI <= 13)      { asm volatile("s_waitcnt vmcnt(4)" ::: "memory"); }
        else if (tI == 14) { asm volatile("s_waitcnt vmcnt(3)" ::: "memory"); }
        else               { asm volatile("s_waitcnt vmcnt(0)" ::: "memory"); }
        __builtin_amdgcn_s_barrier();   // tile tI visible to all waves; all
                                        // waves done reading the write slots
        if (tI + 2 <= 15) {             // A depth-2: stage A(tI+2), slot %3
            STGA((tI + 2) % 3, 0, (tI + 2) << 5);
            STGA((tI + 2) % 3, 1, (tI + 2) << 5);
        }
        if (tI + 3 <= 15) {             // B depth-3: stage B(tI+3), slot %4
            STGB((tI + 3) & 3, (tI + 3) << 5);
        }
        const int sa = tI % 3, sb4 = tI & 3;
        bf16x8 af[4], bf[4];
#pragma unroll
        for (int mi = 0; mi < 4; ++mi)
            af[mi] = FRGA(sa, wm + mi * 16 + l15, quad);
#pragma unroll
        for (int ni = 0; ni < 4; ++ni)
            bf[ni] = FRGB(sb4, wn + ni * 16 + l15, quad);
        __builtin_amdgcn_s_setprio(1);
#pragma unroll
        for (int mi = 0; mi < 4; ++mi)
#pragma unroll
            for (int ni = 0; ni < 4; ++ni)
                acc[mi][ni] = __builtin_amdgcn_mfma_f32_16x16x32_bf16(
                    af[mi], bf[ni], acc[mi][ni], 0, 0, 0);
        __builtin_amdgcn_s_setprio(0);
    }
#undef STGA
#undef STGB
#undef FRGA
#undef FRGB

    // epilogue (WRITE-ONLY): 4 bands of 64 rows x 128 cols via LDS fp32
    // staging (stride 132); nontemporal 512B row stores (clang vector type,
    // not HIP float4 — __builtin_nontemporal_store requires it).
    __syncthreads();
    float* lc = (float*)sm;
#pragma unroll
    for (int h = 0; h < 4; ++h) {
        if (h) __syncthreads();
        if ((w >> 1) == h) {
#pragma unroll
            for (int mi = 0; mi < 4; ++mi)
#pragma unroll
                for (int reg = 0; reg < 4; ++reg) {
                    const int rl = mi * 16 + quad * 4 + reg;
#pragma unroll
                    for (int ni = 0; ni < 4; ++ni)
                        lc[rl * 132 + wn + ni * 16 + l15] = acc[mi][ni][reg];
                }
        }
        __syncthreads();
#pragma unroll
        for (int k = 0; k < 4; ++k) {
            const int r = (t >> 5) + k * 16;
            const int c4 = (t & 31) * 4;
            f32x4 v = *(f32x4*)&lc[r * 132 + c4];
            const int row = m0 + h * 64 + r;
            const float be = beff[b * Cn + row];
            const size_t base = ((size_t)(b * Cn + row)) * Nn + n0 + c4;
            f32x4 o;
            o[0] = v[0] + be;
            o[1] = v[1] + be;
            o[2] = v[2] + be;
            o[3] = v[3] + be;
            __builtin_nontemporal_store(o, (f32x4*)(outF + base));
        }
    }
}

// ---------------------------------------------------------------------------
extern "C" void kernel_launch(void* const* d_in, const int* in_sizes, int n_in,
                              void* d_out, int out_size, void* d_ws, size_t ws_size,
                              hipStream_t stream)
{
    const float* x     = (const float*)d_in[0];
    const float* y     = (const float*)d_in[1];
    const float* wq    = (const float*)d_in[2];
    const float* bq    = (const float*)d_in[3];
    const float* wk    = (const float*)d_in[4];
    const float* bk    = (const float*)d_in[5];
    const float* wv    = (const float*)d_in[6];
    const float* bv    = (const float*)d_in[7];
    const float* gamma = (const float*)d_in[8];
    float* out = (float*)d_out;

    char* ws = (char*)d_ws;
    u16*   xt   = (u16*)  (ws + 0);           // 67,108,864 B : x^T bf16 (B,N,C)
    float* sxp  = (float*)(ws + 67108864);    //  2,097,152 B : partial sums
    float* sx   = (float*)(ws + 69206016);    //     32,768 B
    float* qy   = (float*)(ws + 69238784);    //     32,768 B
    float* sk   = (float*)(ws + 69271552);    //     32,768 B
    float* beff = (float*)(ws + 69304320);    //     32,768 B
    u16*   attn = (u16*)  (ws + 69337088);    //  8,388,608 B : attn bf16
    u16*   wvt  = (u16*)  (ws + 77725696);    //    524,288 B : wv^T bf16
    u16*   weff = (u16*)  (ws + 78249984);    //  8,388,608 B : Weff' bf16
    // total ~86.6 MB

    k_transpose<<<dim3(64, 4, Bn), dim3(256), 0, stream>>>(x, xt, sxp);
    k_sxred<<<dim3(32), dim3(256), 0, stream>>>(sxp, sx);
    k_wvt<<<dim3(8, 8), dim3(256), 0, stream>>>(wv, wvt);
    k_qk<<<dim3(128, Bn, 2), dim3(256), 0, stream>>>(wq, bq, wk, bk, y, sx, qy, sk);
    k_softmax<<<dim3(Bn * Cn), dim3(256), 0, stream>>>(qy, sk, bv, attn, beff, gamma);
    // Weff'[b] = gamma * (attn[b] @ wv)  (as A * wv_t^T), output bf16
    k_gemm<0><<<dim3(4, 4, Bn), dim3(256), 0, stream>>>(
        attn, (size_t)Cn * Cn, wvt, (size_t)0, Cn,
        weff, (size_t)Cn * Cn, nullptr, nullptr, nullptr, gamma);
    // out[b] = Weff'[b] @ x[b] + beff' + x  (residual via MFMA C-init)
    // A ring-3 + B ring-4, 80KB LDS, 2 blocks/CU
    if (hipFuncSetAttribute((const void*)k_gemm2,
                            hipFuncAttributeMaxDynamicSharedMemorySize,
                            81920) == hipSuccess) {
        k_gemm2<<<dim3(32, 2, Bn), dim3(512), 81920, stream>>>(
            weff, xt, out, x, beff);
    } else {
        k_gemm<1><<<dim3(32, 4, Bn), dim3(256), 0, stream>>>(
            weff, (size_t)Cn * Cn, xt, (size_t)Nn * Cn, Nn,
            nullptr, (size_t)0, out, x, beff, gamma);
    }
}

// Round 9
// 329.016 us; speedup vs baseline: 1.0887x; 1.0079x over previous
//
#include <hip/hip_runtime.h>
#include <hip/hip_bf16.h>

#define Bn 16
#define Cn 512
#define Nn 4096

typedef unsigned short u16;
typedef __bf16 bf16x8 __attribute__((ext_vector_type(8)));
typedef float f32x4 __attribute__((ext_vector_type(4)));
typedef unsigned short u16x8 __attribute__((ext_vector_type(8)));

__device__ __forceinline__ u16 f2bf(float f) {
    __hip_bfloat16 h = __float2bfloat16(f);
    return *reinterpret_cast<u16*>(&h);
}

// async global->LDS, 16B per lane; LDS dest is wave-uniform base + lane*16
__device__ __forceinline__ void glds16(const u16* g, u16* l) {
    __builtin_amdgcn_global_load_lds(
        (const __attribute__((address_space(1))) void*)g,
        (__attribute__((address_space(3))) void*)l, 16, 0, 0);
}

// ---------------------------------------------------------------------------
// K1: x (B,C,N) fp32 -> x_t (B,N,C) bf16, plus per-(b,c) partial sums over the
// 64-wide n-tile. 128c x 64n tile: 256B segments on both read and write sides.
// ---------------------------------------------------------------------------
__global__ __launch_bounds__(256) void k_transpose(
    const float* __restrict__ x, u16* __restrict__ xt, float* __restrict__ sxp)
{
    __shared__ float tile[128 * 65];
    const int b = blockIdx.z, c0 = blockIdx.y * 128, n0 = blockIdx.x * 64;
    const int t = threadIdx.x;
    const float* xb = x + ((size_t)(b * Cn + c0)) * Nn + n0;

    float part[8];
#pragma unroll
    for (int r = 0; r < 8; ++r) {
        int cl = (t >> 4) + r * 16;
        int nl = (t & 15) * 4;
        float4 v = *(const float4*)(xb + (size_t)cl * Nn + nl);
        float* tp = &tile[cl * 65 + nl];
        tp[0] = v.x; tp[1] = v.y; tp[2] = v.z; tp[3] = v.w;
        part[r] = (v.x + v.y) + (v.z + v.w);
    }
#pragma unroll
    for (int m = 1; m < 16; m <<= 1) {
#pragma unroll
        for (int r = 0; r < 8; ++r) part[r] += __shfl_xor(part[r], m);
    }
    if ((t & 15) == 0) {
#pragma unroll
        for (int r = 0; r < 8; ++r) {
            int cl = (t >> 4) + r * 16;
            sxp[(size_t)(b * Cn + c0 + cl) * 64 + blockIdx.x] = part[r];
        }
    }
    __syncthreads();
    u16* xtb = xt + ((size_t)(b * Nn + n0)) * Cn + c0;
#pragma unroll
    for (int r = 0; r < 4; ++r) {
        int nl = (t >> 4) + r * 16;
        int c8 = (t & 15) * 8;
        u16x8 hv;
#pragma unroll
        for (int i = 0; i < 8; ++i) hv[i] = f2bf(tile[(c8 + i) * 65 + nl]);
        *(u16x8*)(xtb + (size_t)nl * Cn + c8) = hv;
    }
}

// K1b: reduce 64 n-tile partials -> Sx[b*C+c]
__global__ __launch_bounds__(256) void k_sxred(
    const float* __restrict__ sxp, float* __restrict__ sx)
{
    int i = blockIdx.x * 256 + threadIdx.x;  // 0..8191
    const float4* p = (const float4*)(sxp + (size_t)i * 64);
    float s = 0.f;
#pragma unroll
    for (int j = 0; j < 16; ++j) {
        float4 v = p[j];
        s += (v.x + v.y) + (v.z + v.w);
    }
    sx[i] = s;
}

// K2: qy[b,o] = wq@y + bq ; sk[b,o] = wk@Sx + N*bk. One wave per output.
__global__ __launch_bounds__(256) void k_qk(
    const float* __restrict__ wq, const float* __restrict__ bq,
    const float* __restrict__ wk, const float* __restrict__ bk,
    const float* __restrict__ y, const float* __restrict__ sx,
    float* __restrict__ qy, float* __restrict__ sk)
{
    const int w = threadIdx.x >> 6, lane = threadIdx.x & 63;
    const int o = blockIdx.x * 4 + w;
    const int b = blockIdx.y;
    const int mode = blockIdx.z;
    const float* W = mode ? wk : wq;
    const float* vec = mode ? (sx + b * Cn) : (y + b * Cn);
    float sum = 0.f;
#pragma unroll
    for (int i = 0; i < 8; ++i) {
        int k2 = lane + i * 64;
        sum += W[(size_t)o * Cn + k2] * vec[k2];
    }
#pragma unroll
    for (int m = 1; m < 64; m <<= 1) sum += __shfl_xor(sum, m);
    if (lane == 0) {
        if (mode) sk[b * Cn + o] = sum + 4096.0f * bk[o];
        else      qy[b * Cn + o] = sum + bq[o];
    }
}

// K2b: wv_t[e,d] = bf16(wv[d,e]) via 64x64 LDS tile (coalesced both sides)
__global__ __launch_bounds__(256) void k_wvt(
    const float* __restrict__ wv, u16* __restrict__ wvt)
{
    __shared__ float tl[64 * 65];
    const int d0 = blockIdx.x * 64, e0 = blockIdx.y * 64;
    const int t = threadIdx.x;
#pragma unroll
    for (int r = 0; r < 4; ++r) {
        int d = (t >> 4) + r * 16, e4 = (t & 15) * 4;
        float4 v = *(const float4*)(wv + (size_t)(d0 + d) * Cn + e0 + e4);
        float* p = &tl[d * 65 + e4];
        p[0] = v.x; p[1] = v.y; p[2] = v.z; p[3] = v.w;
    }
    __syncthreads();
#pragma unroll
    for (int r = 0; r < 4; ++r) {
        int e = (t >> 4) + r * 16, d4 = (t & 15) * 4;
        ushort4 h;
        h.x = f2bf(tl[(d4 + 0) * 65 + e]);
        h.y = f2bf(tl[(d4 + 1) * 65 + e]);
        h.z = f2bf(tl[(d4 + 2) * 65 + e]);
        h.w = f2bf(tl[(d4 + 3) * 65 + e]);
        *(ushort4*)(wvt + (size_t)(e0 + e) * Cn + d0 + d4) = h;
    }
}

// ---------------------------------------------------------------------------
// k_weff: FUSED softmax + (attn @ wv) GEMM. Replaces k_softmax + k_gemm<0>.
// Exploits rank-1 energy: attn[c,d] = exp(qy_c*sk_d - mx_c) * invden_c, so
// A-fragments are GENERATED in-register from LDS-resident sk (no A staging,
// no 8MB attn round-trip). Row max is closed-form: q>=0 ? q*max(sk):q*min(sk).
// Also computes beff = gamma*(attn.bv) in the denominator pass (written by
// n-panel-0 blocks only). Output weff carries the gamma fold.
// 128x128 tile, 4 waves, grid (4,4,Bn) — B-side staging identical to k_gemm.
// ---------------------------------------------------------------------------
__global__ __launch_bounds__(256) void k_weff(
    const float* __restrict__ qy, const float* __restrict__ sk,
    const float* __restrict__ bv, const u16* __restrict__ wvt,
    u16* __restrict__ weff, float* __restrict__ beff,
    const float* __restrict__ gamma)
{
    __shared__ u16 lb[128 * 64];          // 16 KB B staging
    __shared__ float sk_l[512], bv_l[512], qy_l[128], mx_l[128], id_l[128];
    __shared__ float red[8];
    const int b = blockIdx.z, m0 = blockIdx.y * 128, n0 = blockIdx.x * 128;
    const int t = threadIdx.x;
    const int lane = t & 63, w = t >> 6;
    const int wm = (w >> 1) * 64, wn = (w & 1) * 64;
    const int l15 = lane & 15, quad = lane >> 4;
    const float gs = gamma[0];

    sk_l[t] = sk[b * Cn + t];
    sk_l[t + 256] = sk[b * Cn + t + 256];
    bv_l[t] = bv[t];
    bv_l[t + 256] = bv[t + 256];
    if (t < 128) qy_l[t] = qy[b * Cn + m0 + t];
    __syncthreads();

    // global max/min of sk (for closed-form per-row max)
    {
        float a = sk_l[t], c2 = sk_l[t + 256];
        float smx = fmaxf(a, c2), smn = fminf(a, c2);
#pragma unroll
        for (int m = 1; m < 64; m <<= 1) {
            smx = fmaxf(smx, __shfl_xor(smx, m));
            smn = fminf(smn, __shfl_xor(smn, m));
        }
        if (lane == 0) { red[w] = smx; red[4 + w] = smn; }
    }
    __syncthreads();
    const float skmax = fmaxf(fmaxf(red[0], red[1]), fmaxf(red[2], red[3]));
    const float skmin = fminf(fminf(red[4], red[5]), fminf(red[6], red[7]));

    // denominator pass: 2 threads per row, 256 d each
    {
        const int r = t >> 1, hf = t & 1;
        const float q = qy_l[r];
        const float mxr = (q >= 0.f) ? q * skmax : q * skmin;
        float den = 0.f, bac = 0.f;
        const int dbase = hf * 256;
#pragma unroll 8
        for (int j = 0; j < 256; ++j) {
            const float e = __expf(q * sk_l[dbase + j] - mxr);
            den += e;
            bac += e * bv_l[dbase + j];
        }
        den += __shfl_xor(den, 1);
        bac += __shfl_xor(bac, 1);
        if (hf == 0) {
            mx_l[r] = mxr;
            const float inv = 1.0f / den;
            id_l[r] = inv;
            if (blockIdx.x == 0) beff[b * Cn + m0 + r] = gs * bac * inv;
        }
    }
    __syncthreads();

    // per-thread row constants for the 4 A-fragment rows
    float qv[4], mxv[4], idv[4];
#pragma unroll
    for (int mi = 0; mi < 4; ++mi) {
        const int row = wm + mi * 16 + l15;
        qv[mi] = qy_l[row];
        mxv[mi] = mx_l[row];
        idv[mi] = id_l[row];
    }

    f32x4 acc[4][4];
#pragma unroll
    for (int i = 0; i < 4; ++i)
#pragma unroll
        for (int j = 0; j < 4; ++j)
            acc[i][j] = (f32x4){0.f, 0.f, 0.f, 0.f};

    const int srow8 = lane >> 3;                 // 0..7
    const int lgcol = ((lane & 7) ^ srow8) * 8;  // logical k-col (swizzled)

    for (int k0 = 0; k0 < 512; k0 += 64) {
        __syncthreads();
#pragma unroll
        for (int j = 0; j < 4; ++j) {
            const int row = w * 32 + j * 8 + srow8;
            const int sb = (w * 256 + j * 64) * 8;
            glds16(wvt + (size_t)(n0 + row) * Cn + k0 + lgcol, lb + sb);
        }
        __syncthreads();

#pragma unroll
        for (int kk2 = 0; kk2 < 2; ++kk2) {
            // shared sk slice for this (kk2, quad): logical d0
            const int d0 = k0 + ((kk2 << 2) + quad) * 8;
            f32x4 s0 = *(const f32x4*)&sk_l[d0];
            f32x4 s1 = *(const f32x4*)&sk_l[d0 + 4];
            bf16x8 af[4], bfr[4];
#pragma unroll
            for (int mi = 0; mi < 4; ++mi) {
                const float q = qv[mi], mo = mxv[mi], iv = idv[mi];
#pragma unroll
                for (int j = 0; j < 4; ++j) {
                    af[mi][j] = (__bf16)(__expf(q * s0[j] - mo) * iv);
                    af[mi][j + 4] = (__bf16)(__expf(q * s1[j] - mo) * iv);
                }
            }
#pragma unroll
            for (int ni = 0; ni < 4; ++ni) {
                const int r = wn + ni * 16 + l15;
                const int pg = ((kk2 << 2) + quad) ^ (l15 & 7);
                bfr[ni] = *(const bf16x8*)&lb[r * 64 + pg * 8];
            }
#pragma unroll
            for (int mi = 0; mi < 4; ++mi)
#pragma unroll
                for (int ni = 0; ni < 4; ++ni)
                    acc[mi][ni] = __builtin_amdgcn_mfma_f32_16x16x32_bf16(
                        af[mi], bfr[ni], acc[mi][ni], 0, 0, 0);
        }
    }

    // epilogue: weff bf16 with gamma fold (same mapping as k_gemm FINAL=0)
#pragma unroll
    for (int mi = 0; mi < 4; ++mi) {
#pragma unroll
        for (int reg = 0; reg < 4; ++reg) {
            const int r = m0 + wm + mi * 16 + quad * 4 + reg;
            const size_t base = (size_t)b * (Cn * Cn) + (size_t)r * Cn;
#pragma unroll
            for (int ni = 0; ni < 4; ++ni) {
                const int cidx = n0 + wn + ni * 16 + l15;
                weff[base + cidx] = f2bf(gs * acc[mi][ni][reg]);
            }
        }
    }
}

// ---------------------------------------------------------------------------
// Shared MFMA GEMM (old 128x128 structure) — fallback for the final GEMM
// (FINAL=1: out = acc + beff' + xres, with weff/beff pre-scaled by gamma).
// ---------------------------------------------------------------------------
template <int FINAL>
__global__ __launch_bounds__(256) void k_gemm(
    const u16* __restrict__ A, size_t strideA,
    const u16* __restrict__ Bt, size_t strideB,
    int N,
    u16* __restrict__ outBf, size_t strideOb,
    float* __restrict__ outF,
    const float* __restrict__ xres,
    const float* __restrict__ beff,
    const float* __restrict__ gamma)
{
    constexpr int K = 512;
    __shared__ float smem_f[8448];
    u16* la = (u16*)smem_f;
    u16* lb = la + 128 * 64;
    const int b = blockIdx.z;
    const int m0 = blockIdx.y * 128;
    const int n0 = blockIdx.x * 128;
    A  += (size_t)b * strideA;
    Bt += (size_t)b * strideB;
    const int t = threadIdx.x;
    const int lane = t & 63;
    const int w = t >> 6;
    const int wm = (w >> 1) * 64, wn = (w & 1) * 64;
    const int l15 = lane & 15, quad = lane >> 4;

    f32x4 acc[4][4];
#pragma unroll
    for (int i = 0; i < 4; ++i)
#pragma unroll
        for (int j = 0; j < 4; ++j)
            acc[i][j] = (f32x4){0.f, 0.f, 0.f, 0.f};

    const int srow8 = lane >> 3;
    const int lgcol = ((lane & 7) ^ srow8) * 8;

    for (int k0 = 0; k0 < K; k0 += 64) {
        __syncthreads();
#pragma unroll
        for (int j = 0; j < 4; ++j) {
            const int row = w * 32 + j * 8 + srow8;
            const int sb = (w * 256 + j * 64) * 8;
            glds16(A  + (size_t)(m0 + row) * K + k0 + lgcol, la + sb);
            glds16(Bt + (size_t)(n0 + row) * K + k0 + lgcol, lb + sb);
        }
        __syncthreads();

#pragma unroll
        for (int kk2 = 0; kk2 < 2; ++kk2) {
            bf16x8 af[4], bfr[4];
#pragma unroll
            for (int mi = 0; mi < 4; ++mi) {
                const int r = wm + mi * 16 + l15;
                const int pg = ((kk2 << 2) + quad) ^ (l15 & 7);
                af[mi] = *(const bf16x8*)&la[r * 64 + pg * 8];
            }
#pragma unroll
            for (int ni = 0; ni < 4; ++ni) {
                const int r = wn + ni * 16 + l15;
                const int pg = ((kk2 << 2) + quad) ^ (l15 & 7);
                bfr[ni] = *(const bf16x8*)&lb[r * 64 + pg * 8];
            }
#pragma unroll
            for (int mi = 0; mi < 4; ++mi)
#pragma unroll
                for (int ni = 0; ni < 4; ++ni)
                    acc[mi][ni] = __builtin_amdgcn_mfma_f32_16x16x32_bf16(
                        af[mi], bfr[ni], acc[mi][ni], 0, 0, 0);
        }
    }

    if (FINAL) {
        float* lc = smem_f;
#pragma unroll
        for (int h = 0; h < 2; ++h) {
            __syncthreads();
            if ((w >> 1) == h) {
#pragma unroll
                for (int mi = 0; mi < 4; ++mi)
#pragma unroll
                    for (int reg = 0; reg < 4; ++reg) {
                        const int rl = mi * 16 + quad * 4 + reg;
#pragma unroll
                        for (int ni = 0; ni < 4; ++ni)
                            lc[rl * 132 + wn + ni * 16 + l15] = acc[mi][ni][reg];
                    }
            }
            __syncthreads();
            const int rb = h * 64;
#pragma unroll
            for (int rr = 0; rr < 8; ++rr) {
                const int rl = rr * 8 + (t >> 5);
                const int c4 = (t & 31) * 4;
                float4 v = *(float4*)&lc[rl * 132 + c4];
                const int r = m0 + rb + rl;
                const float be = beff[b * Cn + r];
                const size_t base = ((size_t)(b * Cn + r)) * N + n0 + c4;
                float4 xr = *(const float4*)(xres + base);
                float4 o;
                o.x = (v.x + be) + xr.x;
                o.y = (v.y + be) + xr.y;
                o.z = (v.z + be) + xr.z;
                o.w = (v.w + be) + xr.w;
                *(float4*)(outF + base) = o;
            }
        }
    } else {
        const float gs = gamma[0];
#pragma unroll
        for (int mi = 0; mi < 4; ++mi) {
#pragma unroll
            for (int reg = 0; reg < 4; ++reg) {
                const int r = m0 + wm + mi * 16 + quad * 4 + reg;
                const size_t base = (size_t)b * strideOb + (size_t)r * N;
#pragma unroll
                for (int ni = 0; ni < 4; ++ni) {
                    const int cidx = n0 + wn + ni * 16 + l15;
                    outBf[base + cidx] = f2bf(gs * acc[mi][ni][reg]);
                }
            }
        }
    }
}

// ---------------------------------------------------------------------------
// k_gemm2 (unchanged from round 7, which measured -21.7us): final GEMM
// out = Weff'@xt + beff' + x. Residual via MFMA C-init; write-only epilogue
// with nontemporal stores; A ring-3 x 16KB (depth 2) + B ring-4 x 8KB
// (depth 3); 80KB LDS -> 2 blocks/CU.
// ---------------------------------------------------------------------------
__global__ __launch_bounds__(512, 4) void k_gemm2(
    const u16* __restrict__ A,    // weff' = gamma*(attn@wv) (B,512,512) bf16
    const u16* __restrict__ Bt,   // xt   (B,4096,512) bf16
    float* __restrict__ outF,
    const float* __restrict__ xres,
    const float* __restrict__ beff)   // pre-scaled by gamma
{
    extern __shared__ u16 sm[];   // 81920 B = A ring-3 x 16KB + B ring-4 x 8KB
    const int b = blockIdx.z;
    const int m0 = blockIdx.y << 8;
    const int n0 = blockIdx.x << 7;
    const int t = threadIdx.x;
    const int lane = t & 63, w = t >> 6;
    const int wm = (w >> 1) << 6, wn = (w & 1) << 6;
    const int l15 = lane & 15, quad = lane >> 4;

    const u16* Ag = A + (size_t)b * Cn * Cn;
    const u16* Bg = Bt + (size_t)b * ((size_t)Nn * Cn);
    const int srow = t >> 2;
    const int scol = (((t & 3) ^ ((srow >> 1) & 3))) << 3;
    const u16* pa = Ag + (size_t)(m0 + srow) * Cn + scol;
    const u16* pb = Bg + (size_t)(n0 + srow) * Cn + scol;
    const int dwo = w * 512;

#define STGA(s, c, k0) \
    glds16(pa + (size_t)(c) * (128 * Cn) + (k0), \
           sm + (s) * 8192 + (c) * 4096 + dwo)
#define STGB(s, k0) glds16(pb + (k0), sm + 24576 + (s) * 4096 + dwo)
#define FRGA(s, row, qd) \
    (*(const bf16x8*)&sm[(s) * 8192 + (row) * 32 + \
                         (((qd) ^ (((row) >> 1) & 3)) << 3)])
#define FRGB(s, row, qd) \
    (*(const bf16x8*)&sm[24576 + (s) * 4096 + (row) * 32 + \
                         (((qd) ^ (((row) >> 1) & 3)) << 3)])

    f32x4 acc[4][4];
#pragma unroll
    for (int mi = 0; mi < 4; ++mi)
#pragma unroll
        for (int reg = 0; reg < 4; ++reg) {
            const int row = m0 + wm + mi * 16 + quad * 4 + reg;
            const float* xr =
                xres + ((size_t)(b * Cn + row)) * Nn + n0 + wn + l15;
#pragma unroll
            for (int ni = 0; ni < 4; ++ni)
                acc[mi][ni][reg] = xr[ni * 16];
        }
    asm volatile("" ::: "memory");
    __builtin_amdgcn_sched_barrier(0);

    STGB(0, 0);
    STGA(0, 0, 0); STGA(0, 1, 0);
    STGB(1, 32);
    STGA(1, 0, 32); STGA(1, 1, 32);
    STGB(2, 64);

#pragma unroll
    for (int tI = 0; tI < 16; ++tI) {
        if (tI <= 13)      { asm volatile("s_waitcnt vmcnt(4)" ::: "memory"); }
        else if (tI == 14) { asm volatile("s_waitcnt vmcnt(3)" ::: "memory"); }
        else               { asm volatile("s_waitcnt vmcnt(0)" ::: "memory"); }
        __builtin_amdgcn_s_barrier();
        if (tI + 2 <= 15) {
            STGA((tI + 2) % 3, 0, (tI + 2) << 5);
            STGA((tI + 2) % 3, 1, (tI + 2) << 5);
        }
        if (tI + 3 <= 15) {
            STGB((tI + 3) & 3, (tI + 3) << 5);
        }
        const int sa = tI % 3, sb4 = tI & 3;
        bf16x8 af[4], bf[4];
#pragma unroll
        for (int mi = 0; mi < 4; ++mi)
            af[mi] = FRGA(sa, wm + mi * 16 + l15, quad);
#pragma unroll
        for (int ni = 0; ni < 4; ++ni)
            bf[ni] = FRGB(sb4, wn + ni * 16 + l15, quad);
        __builtin_amdgcn_s_setprio(1);
#pragma unroll
        for (int mi = 0; mi < 4; ++mi)
#pragma unroll
            for (int ni = 0; ni < 4; ++ni)
                acc[mi][ni] = __builtin_amdgcn_mfma_f32_16x16x32_bf16(
                    af[mi], bf[ni], acc[mi][ni], 0, 0, 0);
        __builtin_amdgcn_s_setprio(0);
    }
#undef STGA
#undef STGB
#undef FRGA
#undef FRGB

    __syncthreads();
    float* lc = (float*)sm;
#pragma unroll
    for (int h = 0; h < 4; ++h) {
        if (h) __syncthreads();
        if ((w >> 1) == h) {
#pragma unroll
            for (int mi = 0; mi < 4; ++mi)
#pragma unroll
                for (int reg = 0; reg < 4; ++reg) {
                    const int rl = mi * 16 + quad * 4 + reg;
#pragma unroll
                    for (int ni = 0; ni < 4; ++ni)
                        lc[rl * 132 + wn + ni * 16 + l15] = acc[mi][ni][reg];
                }
        }
        __syncthreads();
#pragma unroll
        for (int k = 0; k < 4; ++k) {
            const int r = (t >> 5) + k * 16;
            const int c4 = (t & 31) * 4;
            f32x4 v = *(f32x4*)&lc[r * 132 + c4];
            const int row = m0 + h * 64 + r;
            const float be = beff[b * Cn + row];
            const size_t base = ((size_t)(b * Cn + row)) * Nn + n0 + c4;
            f32x4 o;
            o[0] = v[0] + be;
            o[1] = v[1] + be;
            o[2] = v[2] + be;
            o[3] = v[3] + be;
            __builtin_nontemporal_store(o, (f32x4*)(outF + base));
        }
    }
}

// ---------------------------------------------------------------------------
extern "C" void kernel_launch(void* const* d_in, const int* in_sizes, int n_in,
                              void* d_out, int out_size, void* d_ws, size_t ws_size,
                              hipStream_t stream)
{
    const float* x     = (const float*)d_in[0];
    const float* y     = (const float*)d_in[1];
    const float* wq    = (const float*)d_in[2];
    const float* bq    = (const float*)d_in[3];
    const float* wk    = (const float*)d_in[4];
    const float* bk    = (const float*)d_in[5];
    const float* wv    = (const float*)d_in[6];
    const float* bv    = (const float*)d_in[7];
    const float* gamma = (const float*)d_in[8];
    float* out = (float*)d_out;

    char* ws = (char*)d_ws;
    u16*   xt   = (u16*)  (ws + 0);           // 67,108,864 B : x^T bf16 (B,N,C)
    float* sxp  = (float*)(ws + 67108864);    //  2,097,152 B : partial sums
    float* sx   = (float*)(ws + 69206016);    //     32,768 B
    float* qy   = (float*)(ws + 69238784);    //     32,768 B
    float* sk   = (float*)(ws + 69271552);    //     32,768 B
    float* beff = (float*)(ws + 69304320);    //     32,768 B
    u16*   wvt  = (u16*)  (ws + 77725696);    //    524,288 B : wv^T bf16
    u16*   weff = (u16*)  (ws + 78249984);    //  8,388,608 B : Weff' bf16

    k_transpose<<<dim3(64, 4, Bn), dim3(256), 0, stream>>>(x, xt, sxp);
    k_sxred<<<dim3(32), dim3(256), 0, stream>>>(sxp, sx);
    k_wvt<<<dim3(8, 8), dim3(256), 0, stream>>>(wv, wvt);
    k_qk<<<dim3(128, Bn, 2), dim3(256), 0, stream>>>(wq, bq, wk, bk, y, sx, qy, sk);
    // FUSED: weff' = gamma*(softmax(qy x sk) @ wv), beff' = gamma*(attn.bv)
    k_weff<<<dim3(4, 4, Bn), dim3(256), 0, stream>>>(
        qy, sk, bv, wvt, weff, beff, gamma);
    // out[b] = Weff'[b] @ x[b] + beff' + x  (residual via MFMA C-init)
    if (hipFuncSetAttribute((const void*)k_gemm2,
                            hipFuncAttributeMaxDynamicSharedMemorySize,
                            81920) == hipSuccess) {
        k_gemm2<<<dim3(32, 2, Bn), dim3(512), 81920, stream>>>(
            weff, xt, out, x, beff);
    } else {
        k_gemm<1><<<dim3(32, 4, Bn), dim3(256), 0, stream>>>(
            weff, (size_t)Cn * Cn, xt, (size_t)Nn * Cn, Nn,
            nullptr, (size_t)0, out, x, beff, gamma);
    }
}

// Round 10
// 326.123 us; speedup vs baseline: 1.0983x; 1.0089x over previous
//
#include <hip/hip_runtime.h>
#include <hip/hip_bf16.h>

#define Bn 16
#define Cn 512
#define Nn 4096

typedef unsigned short u16;
typedef __bf16 bf16x8 __attribute__((ext_vector_type(8)));
typedef float f32x4 __attribute__((ext_vector_type(4)));
typedef unsigned short u16x8 __attribute__((ext_vector_type(8)));

__device__ __forceinline__ u16 f2bf(float f) {
    __hip_bfloat16 h = __float2bfloat16(f);
    return *reinterpret_cast<u16*>(&h);
}

// async global->LDS, 16B per lane; LDS dest is wave-uniform base + lane*16
__device__ __forceinline__ void glds16(const u16* g, u16* l) {
    __builtin_amdgcn_global_load_lds(
        (const __attribute__((address_space(1))) void*)g,
        (__attribute__((address_space(3))) void*)l, 16, 0, 0);
}

// ---------------------------------------------------------------------------
// K1: x (B,C,N) fp32 -> x_t (B,N,C) bf16, plus per-(b,c) partial sums over the
// 64-wide n-tile. 128c x 64n tile: 256B segments on both read and write sides.
// ---------------------------------------------------------------------------
__global__ __launch_bounds__(256) void k_transpose(
    const float* __restrict__ x, u16* __restrict__ xt, float* __restrict__ sxp)
{
    __shared__ float tile[128 * 65];
    const int b = blockIdx.z, c0 = blockIdx.y * 128, n0 = blockIdx.x * 64;
    const int t = threadIdx.x;
    const float* xb = x + ((size_t)(b * Cn + c0)) * Nn + n0;

    float part[8];
#pragma unroll
    for (int r = 0; r < 8; ++r) {
        int cl = (t >> 4) + r * 16;
        int nl = (t & 15) * 4;
        float4 v = *(const float4*)(xb + (size_t)cl * Nn + nl);
        float* tp = &tile[cl * 65 + nl];
        tp[0] = v.x; tp[1] = v.y; tp[2] = v.z; tp[3] = v.w;
        part[r] = (v.x + v.y) + (v.z + v.w);
    }
#pragma unroll
    for (int m = 1; m < 16; m <<= 1) {
#pragma unroll
        for (int r = 0; r < 8; ++r) part[r] += __shfl_xor(part[r], m);
    }
    if ((t & 15) == 0) {
#pragma unroll
        for (int r = 0; r < 8; ++r) {
            int cl = (t >> 4) + r * 16;
            sxp[(size_t)(b * Cn + c0 + cl) * 64 + blockIdx.x] = part[r];
        }
    }
    __syncthreads();
    u16* xtb = xt + ((size_t)(b * Nn + n0)) * Cn + c0;
#pragma unroll
    for (int r = 0; r < 4; ++r) {
        int nl = (t >> 4) + r * 16;
        int c8 = (t & 15) * 8;
        u16x8 hv;
#pragma unroll
        for (int i = 0; i < 8; ++i) hv[i] = f2bf(tile[(c8 + i) * 65 + nl]);
        *(u16x8*)(xtb + (size_t)nl * Cn + c8) = hv;
    }
}

// K1b: reduce 64 n-tile partials -> Sx[b*C+c]
__global__ __launch_bounds__(256) void k_sxred(
    const float* __restrict__ sxp, float* __restrict__ sx)
{
    int i = blockIdx.x * 256 + threadIdx.x;  // 0..8191
    const float4* p = (const float4*)(sxp + (size_t)i * 64);
    float s = 0.f;
#pragma unroll
    for (int j = 0; j < 16; ++j) {
        float4 v = p[j];
        s += (v.x + v.y) + (v.z + v.w);
    }
    sx[i] = s;
}

// K2: qy[b,o] = wq@y + bq ; sk[b,o] = wk@Sx + N*bk. One wave per output.
__global__ __launch_bounds__(256) void k_qk(
    const float* __restrict__ wq, const float* __restrict__ bq,
    const float* __restrict__ wk, const float* __restrict__ bk,
    const float* __restrict__ y, const float* __restrict__ sx,
    float* __restrict__ qy, float* __restrict__ sk)
{
    const int w = threadIdx.x >> 6, lane = threadIdx.x & 63;
    const int o = blockIdx.x * 4 + w;
    const int b = blockIdx.y;
    const int mode = blockIdx.z;
    const float* W = mode ? wk : wq;
    const float* vec = mode ? (sx + b * Cn) : (y + b * Cn);
    float sum = 0.f;
#pragma unroll
    for (int i = 0; i < 8; ++i) {
        int k2 = lane + i * 64;
        sum += W[(size_t)o * Cn + k2] * vec[k2];
    }
#pragma unroll
    for (int m = 1; m < 64; m <<= 1) sum += __shfl_xor(sum, m);
    if (lane == 0) {
        if (mode) sk[b * Cn + o] = sum + 4096.0f * bk[o];
        else      qy[b * Cn + o] = sum + bq[o];
    }
}

// K2b: wv_t[e,d] = bf16(wv[d,e]) via 64x64 LDS tile (coalesced both sides)
__global__ __launch_bounds__(256) void k_wvt(
    const float* __restrict__ wv, u16* __restrict__ wvt)
{
    __shared__ float tl[64 * 65];
    const int d0 = blockIdx.x * 64, e0 = blockIdx.y * 64;
    const int t = threadIdx.x;
#pragma unroll
    for (int r = 0; r < 4; ++r) {
        int d = (t >> 4) + r * 16, e4 = (t & 15) * 4;
        float4 v = *(const float4*)(wv + (size_t)(d0 + d) * Cn + e0 + e4);
        float* p = &tl[d * 65 + e4];
        p[0] = v.x; p[1] = v.y; p[2] = v.z; p[3] = v.w;
    }
    __syncthreads();
#pragma unroll
    for (int r = 0; r < 4; ++r) {
        int e = (t >> 4) + r * 16, d4 = (t & 15) * 4;
        ushort4 h;
        h.x = f2bf(tl[(d4 + 0) * 65 + e]);
        h.y = f2bf(tl[(d4 + 1) * 65 + e]);
        h.z = f2bf(tl[(d4 + 2) * 65 + e]);
        h.w = f2bf(tl[(d4 + 3) * 65 + e]);
        *(ushort4*)(wvt + (size_t)(e0 + e) * Cn + d0 + d4) = h;
    }
}

// ---------------------------------------------------------------------------
// k_weff (round 10): FUSED softmax + (attn @ wv) GEMM, occupancy-fixed.
// Round-9 ran grid 256 = 1 block/CU, 1 wave/SIMD — zero latency hiding.
// Now: n-tile 64, grid (8,4,Bn) = 512 blocks = 2 blocks/CU; 4 waves stacked
// on m (wave-tile 32x64, acc[2][4]). Same rank-1-energy A-fragment
// generation, same closed-form row max, same XOR-swizzle invariant on the
// B staging (slot = row*8+(lane&7), src col = ((lane&7)^(row&7))*8).
// beff written by blockIdx.x==0 blocks only. Denominator pass redundant per
// n-block (cheap, keeps blocks independent).
// ---------------------------------------------------------------------------
__global__ __launch_bounds__(256) void k_weff(
    const float* __restrict__ qy, const float* __restrict__ sk,
    const float* __restrict__ bv, const u16* __restrict__ wvt,
    u16* __restrict__ weff, float* __restrict__ beff,
    const float* __restrict__ gamma)
{
    __shared__ u16 lb[64 * 64];           // 8 KB B staging (64 n-rows x 64 k)
    __shared__ float sk_l[512], bv_l[512], qy_l[128], mx_l[128], id_l[128];
    __shared__ float red[8];
    const int b = blockIdx.z, m0 = blockIdx.y * 128, n0 = blockIdx.x * 64;
    const int t = threadIdx.x;
    const int lane = t & 63, w = t >> 6;
    const int wm = w * 32;                // wave-tile: 32 m-rows x 64 n-cols
    const int l15 = lane & 15, quad = lane >> 4;
    const float gs = gamma[0];

    sk_l[t] = sk[b * Cn + t];
    sk_l[t + 256] = sk[b * Cn + t + 256];
    bv_l[t] = bv[t];
    bv_l[t + 256] = bv[t + 256];
    if (t < 128) qy_l[t] = qy[b * Cn + m0 + t];
    __syncthreads();

    // global max/min of sk (for closed-form per-row max)
    {
        float a = sk_l[t], c2 = sk_l[t + 256];
        float smx = fmaxf(a, c2), smn = fminf(a, c2);
#pragma unroll
        for (int m = 1; m < 64; m <<= 1) {
            smx = fmaxf(smx, __shfl_xor(smx, m));
            smn = fminf(smn, __shfl_xor(smn, m));
        }
        if (lane == 0) { red[w] = smx; red[4 + w] = smn; }
    }
    __syncthreads();
    const float skmax = fmaxf(fmaxf(red[0], red[1]), fmaxf(red[2], red[3]));
    const float skmin = fminf(fminf(red[4], red[5]), fminf(red[6], red[7]));

    // denominator pass: 2 threads per row, 256 d each
    {
        const int r = t >> 1, hf = t & 1;
        const float q = qy_l[r];
        const float mxr = (q >= 0.f) ? q * skmax : q * skmin;
        float den = 0.f, bac = 0.f;
        const int dbase = hf * 256;
#pragma unroll 8
        for (int j = 0; j < 256; ++j) {
            const float e = __expf(q * sk_l[dbase + j] - mxr);
            den += e;
            bac += e * bv_l[dbase + j];
        }
        den += __shfl_xor(den, 1);
        bac += __shfl_xor(bac, 1);
        if (hf == 0) {
            mx_l[r] = mxr;
            const float inv = 1.0f / den;
            id_l[r] = inv;
            if (blockIdx.x == 0) beff[b * Cn + m0 + r] = gs * bac * inv;
        }
    }
    __syncthreads();

    // per-thread row constants for the 2 A-fragment rows
    float qv[2], mxv[2], idv[2];
#pragma unroll
    for (int mi = 0; mi < 2; ++mi) {
        const int row = wm + mi * 16 + l15;
        qv[mi] = qy_l[row];
        mxv[mi] = mx_l[row];
        idv[mi] = id_l[row];
    }

    f32x4 acc[2][4];
#pragma unroll
    for (int i = 0; i < 2; ++i)
#pragma unroll
        for (int j = 0; j < 4; ++j)
            acc[i][j] = (f32x4){0.f, 0.f, 0.f, 0.f};

    const int srow8 = lane >> 3;                 // 0..7
    const int lgcol = ((lane & 7) ^ srow8) * 8;  // logical k-col (swizzled)

    for (int k0 = 0; k0 < 512; k0 += 64) {
        __syncthreads();
        // stage 64 rows x 64 k bf16 (8KB): 2 glds16/thread.
        // row = w*16 + j*8 + srow8  (4 waves x j{0,1} x srow8 -> 64 rows)
        // slot = w*128 + j*64 + lane = row*8 + (lane&7)  -> swizzle invariant
#pragma unroll
        for (int j = 0; j < 2; ++j) {
            const int row = w * 16 + j * 8 + srow8;
            const int sb = (w * 128 + j * 64) * 8;
            glds16(wvt + (size_t)(n0 + row) * Cn + k0 + lgcol, lb + sb);
        }
        __syncthreads();

#pragma unroll
        for (int kk2 = 0; kk2 < 2; ++kk2) {
            // shared sk slice for this (kk2, quad): logical d0
            const int d0 = k0 + ((kk2 << 2) + quad) * 8;
            f32x4 s0 = *(const f32x4*)&sk_l[d0];
            f32x4 s1 = *(const f32x4*)&sk_l[d0 + 4];
            bf16x8 af[2], bfr[4];
#pragma unroll
            for (int mi = 0; mi < 2; ++mi) {
                const float q = qv[mi], mo = mxv[mi], iv = idv[mi];
#pragma unroll
                for (int j = 0; j < 4; ++j) {
                    af[mi][j] = (__bf16)(__expf(q * s0[j] - mo) * iv);
                    af[mi][j + 4] = (__bf16)(__expf(q * s1[j] - mo) * iv);
                }
            }
#pragma unroll
            for (int ni = 0; ni < 4; ++ni) {
                const int r = ni * 16 + l15;
                const int pg = ((kk2 << 2) + quad) ^ (l15 & 7);
                bfr[ni] = *(const bf16x8*)&lb[r * 64 + pg * 8];
            }
#pragma unroll
            for (int mi = 0; mi < 2; ++mi)
#pragma unroll
                for (int ni = 0; ni < 4; ++ni)
                    acc[mi][ni] = __builtin_amdgcn_mfma_f32_16x16x32_bf16(
                        af[mi], bfr[ni], acc[mi][ni], 0, 0, 0);
        }
    }

    // epilogue: weff bf16 with gamma fold
#pragma unroll
    for (int mi = 0; mi < 2; ++mi) {
#pragma unroll
        for (int reg = 0; reg < 4; ++reg) {
            const int r = m0 + wm + mi * 16 + quad * 4 + reg;
            const size_t base = (size_t)b * (Cn * Cn) + (size_t)r * Cn;
#pragma unroll
            for (int ni = 0; ni < 4; ++ni) {
                const int cidx = n0 + ni * 16 + l15;
                weff[base + cidx] = f2bf(gs * acc[mi][ni][reg]);
            }
        }
    }
}

// ---------------------------------------------------------------------------
// Shared MFMA GEMM (old 128x128 structure) — fallback for the final GEMM
// (FINAL=1: out = acc + beff' + xres, with weff/beff pre-scaled by gamma).
// ---------------------------------------------------------------------------
template <int FINAL>
__global__ __launch_bounds__(256) void k_gemm(
    const u16* __restrict__ A, size_t strideA,
    const u16* __restrict__ Bt, size_t strideB,
    int N,
    u16* __restrict__ outBf, size_t strideOb,
    float* __restrict__ outF,
    const float* __restrict__ xres,
    const float* __restrict__ beff,
    const float* __restrict__ gamma)
{
    constexpr int K = 512;
    __shared__ float smem_f[8448];
    u16* la = (u16*)smem_f;
    u16* lb = la + 128 * 64;
    const int b = blockIdx.z;
    const int m0 = blockIdx.y * 128;
    const int n0 = blockIdx.x * 128;
    A  += (size_t)b * strideA;
    Bt += (size_t)b * strideB;
    const int t = threadIdx.x;
    const int lane = t & 63;
    const int w = t >> 6;
    const int wm = (w >> 1) * 64, wn = (w & 1) * 64;
    const int l15 = lane & 15, quad = lane >> 4;

    f32x4 acc[4][4];
#pragma unroll
    for (int i = 0; i < 4; ++i)
#pragma unroll
        for (int j = 0; j < 4; ++j)
            acc[i][j] = (f32x4){0.f, 0.f, 0.f, 0.f};

    const int srow8 = lane >> 3;
    const int lgcol = ((lane & 7) ^ srow8) * 8;

    for (int k0 = 0; k0 < K; k0 += 64) {
        __syncthreads();
#pragma unroll
        for (int j = 0; j < 4; ++j) {
            const int row = w * 32 + j * 8 + srow8;
            const int sb = (w * 256 + j * 64) * 8;
            glds16(A  + (size_t)(m0 + row) * K + k0 + lgcol, la + sb);
            glds16(Bt + (size_t)(n0 + row) * K + k0 + lgcol, lb + sb);
        }
        __syncthreads();

#pragma unroll
        for (int kk2 = 0; kk2 < 2; ++kk2) {
            bf16x8 af[4], bfr[4];
#pragma unroll
            for (int mi = 0; mi < 4; ++mi) {
                const int r = wm + mi * 16 + l15;
                const int pg = ((kk2 << 2) + quad) ^ (l15 & 7);
                af[mi] = *(const bf16x8*)&la[r * 64 + pg * 8];
            }
#pragma unroll
            for (int ni = 0; ni < 4; ++ni) {
                const int r = wn + ni * 16 + l15;
                const int pg = ((kk2 << 2) + quad) ^ (l15 & 7);
                bfr[ni] = *(const bf16x8*)&lb[r * 64 + pg * 8];
            }
#pragma unroll
            for (int mi = 0; mi < 4; ++mi)
#pragma unroll
                for (int ni = 0; ni < 4; ++ni)
                    acc[mi][ni] = __builtin_amdgcn_mfma_f32_16x16x32_bf16(
                        af[mi], bfr[ni], acc[mi][ni], 0, 0, 0);
        }
    }

    if (FINAL) {
        float* lc = smem_f;
#pragma unroll
        for (int h = 0; h < 2; ++h) {
            __syncthreads();
            if ((w >> 1) == h) {
#pragma unroll
                for (int mi = 0; mi < 4; ++mi)
#pragma unroll
                    for (int reg = 0; reg < 4; ++reg) {
                        const int rl = mi * 16 + quad * 4 + reg;
#pragma unroll
                        for (int ni = 0; ni < 4; ++ni)
                            lc[rl * 132 + wn + ni * 16 + l15] = acc[mi][ni][reg];
                    }
            }
            __syncthreads();
            const int rb = h * 64;
#pragma unroll
            for (int rr = 0; rr < 8; ++rr) {
                const int rl = rr * 8 + (t >> 5);
                const int c4 = (t & 31) * 4;
                float4 v = *(float4*)&lc[rl * 132 + c4];
                const int r = m0 + rb + rl;
                const float be = beff[b * Cn + r];
                const size_t base = ((size_t)(b * Cn + r)) * N + n0 + c4;
                float4 xr = *(const float4*)(xres + base);
                float4 o;
                o.x = (v.x + be) + xr.x;
                o.y = (v.y + be) + xr.y;
                o.z = (v.z + be) + xr.z;
                o.w = (v.w + be) + xr.w;
                *(float4*)(outF + base) = o;
            }
        }
    } else {
        const float gs = gamma[0];
#pragma unroll
        for (int mi = 0; mi < 4; ++mi) {
#pragma unroll
            for (int reg = 0; reg < 4; ++reg) {
                const int r = m0 + wm + mi * 16 + quad * 4 + reg;
                const size_t base = (size_t)b * strideOb + (size_t)r * N;
#pragma unroll
                for (int ni = 0; ni < 4; ++ni) {
                    const int cidx = n0 + wn + ni * 16 + l15;
                    outBf[base + cidx] = f2bf(gs * acc[mi][ni][reg]);
                }
            }
        }
    }
}

// ---------------------------------------------------------------------------
// k_gemm2 (unchanged from round 7, which measured -21.7us): final GEMM
// out = Weff'@xt + beff' + x. Residual via MFMA C-init; write-only epilogue
// with nontemporal stores; A ring-3 x 16KB (depth 2) + B ring-4 x 8KB
// (depth 3); 80KB LDS -> 2 blocks/CU.
// ---------------------------------------------------------------------------
__global__ __launch_bounds__(512, 4) void k_gemm2(
    const u16* __restrict__ A,    // weff' = gamma*(attn@wv) (B,512,512) bf16
    const u16* __restrict__ Bt,   // xt   (B,4096,512) bf16
    float* __restrict__ outF,
    const float* __restrict__ xres,
    const float* __restrict__ beff)   // pre-scaled by gamma
{
    extern __shared__ u16 sm[];   // 81920 B = A ring-3 x 16KB + B ring-4 x 8KB
    const int b = blockIdx.z;
    const int m0 = blockIdx.y << 8;
    const int n0 = blockIdx.x << 7;
    const int t = threadIdx.x;
    const int lane = t & 63, w = t >> 6;
    const int wm = (w >> 1) << 6, wn = (w & 1) << 6;
    const int l15 = lane & 15, quad = lane >> 4;

    const u16* Ag = A + (size_t)b * Cn * Cn;
    const u16* Bg = Bt + (size_t)b * ((size_t)Nn * Cn);
    const int srow = t >> 2;
    const int scol = (((t & 3) ^ ((srow >> 1) & 3))) << 3;
    const u16* pa = Ag + (size_t)(m0 + srow) * Cn + scol;
    const u16* pb = Bg + (size_t)(n0 + srow) * Cn + scol;
    const int dwo = w * 512;

#define STGA(s, c, k0) \
    glds16(pa + (size_t)(c) * (128 * Cn) + (k0), \
           sm + (s) * 8192 + (c) * 4096 + dwo)
#define STGB(s, k0) glds16(pb + (k0), sm + 24576 + (s) * 4096 + dwo)
#define FRGA(s, row, qd) \
    (*(const bf16x8*)&sm[(s) * 8192 + (row) * 32 + \
                         (((qd) ^ (((row) >> 1) & 3)) << 3)])
#define FRGB(s, row, qd) \
    (*(const bf16x8*)&sm[24576 + (s) * 4096 + (row) * 32 + \
                         (((qd) ^ (((row) >> 1) & 3)) << 3)])

    f32x4 acc[4][4];
#pragma unroll
    for (int mi = 0; mi < 4; ++mi)
#pragma unroll
        for (int reg = 0; reg < 4; ++reg) {
            const int row = m0 + wm + mi * 16 + quad * 4 + reg;
            const float* xr =
                xres + ((size_t)(b * Cn + row)) * Nn + n0 + wn + l15;
#pragma unroll
            for (int ni = 0; ni < 4; ++ni)
                acc[mi][ni][reg] = xr[ni * 16];
        }
    asm volatile("" ::: "memory");
    __builtin_amdgcn_sched_barrier(0);

    STGB(0, 0);
    STGA(0, 0, 0); STGA(0, 1, 0);
    STGB(1, 32);
    STGA(1, 0, 32); STGA(1, 1, 32);
    STGB(2, 64);

#pragma unroll
    for (int tI = 0; tI < 16; ++tI) {
        if (tI <= 13)      { asm volatile("s_waitcnt vmcnt(4)" ::: "memory"); }
        else if (tI == 14) { asm volatile("s_waitcnt vmcnt(3)" ::: "memory"); }
        else               { asm volatile("s_waitcnt vmcnt(0)" ::: "memory"); }
        __builtin_amdgcn_s_barrier();
        if (tI + 2 <= 15) {
            STGA((tI + 2) % 3, 0, (tI + 2) << 5);
            STGA((tI + 2) % 3, 1, (tI + 2) << 5);
        }
        if (tI + 3 <= 15) {
            STGB((tI + 3) & 3, (tI + 3) << 5);
        }
        const int sa = tI % 3, sb4 = tI & 3;
        bf16x8 af[4], bf[4];
#pragma unroll
        for (int mi = 0; mi < 4; ++mi)
            af[mi] = FRGA(sa, wm + mi * 16 + l15, quad);
#pragma unroll
        for (int ni = 0; ni < 4; ++ni)
            bf[ni] = FRGB(sb4, wn + ni * 16 + l15, quad);
        __builtin_amdgcn_s_setprio(1);
#pragma unroll
        for (int mi = 0; mi < 4; ++mi)
#pragma unroll
            for (int ni = 0; ni < 4; ++ni)
                acc[mi][ni] = __builtin_amdgcn_mfma_f32_16x16x32_bf16(
                    af[mi], bf[ni], acc[mi][ni], 0, 0, 0);
        __builtin_amdgcn_s_setprio(0);
    }
#undef STGA
#undef STGB
#undef FRGA
#undef FRGB

    __syncthreads();
    float* lc = (float*)sm;
#pragma unroll
    for (int h = 0; h < 4; ++h) {
        if (h) __syncthreads();
        if ((w >> 1) == h) {
#pragma unroll
            for (int mi = 0; mi < 4; ++mi)
#pragma unroll
                for (int reg = 0; reg < 4; ++reg) {
                    const int rl = mi * 16 + quad * 4 + reg;
#pragma unroll
                    for (int ni = 0; ni < 4; ++ni)
                        lc[rl * 132 + wn + ni * 16 + l15] = acc[mi][ni][reg];
                }
        }
        __syncthreads();
#pragma unroll
        for (int k = 0; k < 4; ++k) {
            const int r = (t >> 5) + k * 16;
            const int c4 = (t & 31) * 4;
            f32x4 v = *(f32x4*)&lc[r * 132 + c4];
            const int row = m0 + h * 64 + r;
            const float be = beff[b * Cn + row];
            const size_t base = ((size_t)(b * Cn + row)) * Nn + n0 + c4;
            f32x4 o;
            o[0] = v[0] + be;
            o[1] = v[1] + be;
            o[2] = v[2] + be;
            o[3] = v[3] + be;
            __builtin_nontemporal_store(o, (f32x4*)(outF + base));
        }
    }
}

// ---------------------------------------------------------------------------
extern "C" void kernel_launch(void* const* d_in, const int* in_sizes, int n_in,
                              void* d_out, int out_size, void* d_ws, size_t ws_size,
                              hipStream_t stream)
{
    const float* x     = (const float*)d_in[0];
    const float* y     = (const float*)d_in[1];
    const float* wq    = (const float*)d_in[2];
    const float* bq    = (const float*)d_in[3];
    const float* wk    = (const float*)d_in[4];
    const float* bk    = (const float*)d_in[5];
    const float* wv    = (const float*)d_in[6];
    const float* bv    = (const float*)d_in[7];
    const float* gamma = (const float*)d_in[8];
    float* out = (float*)d_out;

    char* ws = (char*)d_ws;
    u16*   xt   = (u16*)  (ws + 0);           // 67,108,864 B : x^T bf16 (B,N,C)
    float* sxp  = (float*)(ws + 67108864);    //  2,097,152 B : partial sums
    float* sx   = (float*)(ws + 69206016);    //     32,768 B
    float* qy   = (float*)(ws + 69238784);    //     32,768 B
    float* sk   = (float*)(ws + 69271552);    //     32,768 B
    float* beff = (float*)(ws + 69304320);    //     32,768 B
    u16*   wvt  = (u16*)  (ws + 77725696);    //    524,288 B : wv^T bf16
    u16*   weff = (u16*)  (ws + 78249984);    //  8,388,608 B : Weff' bf16

    k_transpose<<<dim3(64, 4, Bn), dim3(256), 0, stream>>>(x, xt, sxp);
    k_sxred<<<dim3(32), dim3(256), 0, stream>>>(sxp, sx);
    k_wvt<<<dim3(8, 8), dim3(256), 0, stream>>>(wv, wvt);
    k_qk<<<dim3(128, Bn, 2), dim3(256), 0, stream>>>(wq, bq, wk, bk, y, sx, qy, sk);
    // FUSED: weff' = gamma*(softmax(qy x sk) @ wv), beff' = gamma*(attn.bv)
    // n-tile 64 -> 512 blocks = 2 blocks/CU (was 256 = 1/CU, latency-exposed)
    k_weff<<<dim3(8, 4, Bn), dim3(256), 0, stream>>>(
        qy, sk, bv, wvt, weff, beff, gamma);
    // out[b] = Weff'[b] @ x[b] + beff' + x  (residual via MFMA C-init)
    if (hipFuncSetAttribute((const void*)k_gemm2,
                            hipFuncAttributeMaxDynamicSharedMemorySize,
                            81920) == hipSuccess) {
        k_gemm2<<<dim3(32, 2, Bn), dim3(512), 81920, stream>>>(
            weff, xt, out, x, beff);
    } else {
        k_gemm<1><<<dim3(32, 4, Bn), dim3(256), 0, stream>>>(
            weff, (size_t)Cn * Cn, xt, (size_t)Nn * Cn, Nn,
            nullptr, (size_t)0, out, x, beff, gamma);
    }
}